// Round 6
// baseline (753.860 us; speedup 1.0000x reference)
//
#include <hip/hip_runtime.h>
#include <math.h>

#define NPIX 262144   // 512*512
#define FSTR 513      // LDS column stride for batch-8 FFT (pad 512+1)

__device__ __forceinline__ int brev9(int i) { return (int)(__brev((unsigned)i) >> 23); }

__device__ __forceinline__ void init_tw(float* twr, float* twi, int t) {
  if (t < 256) {
    float ang = -3.14159265358979323846f * (float)t / 256.0f;
    float s, c;
    sincosf(ang, &s, &c);
    twr[t] = c; twi[t] = s;
  }
}

// 8 x 512-pt radix-2 DIT FFTs in LDS, column-major: element p of FFT c at
// [c*FSTR + p]. 256 threads: c = t>>5, 32 threads x 8 butterflies/stage/FFT.
template<bool FWD>
__device__ __forceinline__ void fft512x8(float* __restrict__ sr, float* __restrict__ si,
                                         const float* __restrict__ twr,
                                         const float* __restrict__ twi, int t) {
  const int c  = t >> 5;
  const int k0 = t & 31;
  float* cr = sr + c * FSTR;
  float* ci = si + c * FSTR;
  #pragma unroll
  for (int s = 0; s < 9; s++) {
    const int half = 1 << s;
    __syncthreads();
    #pragma unroll
    for (int m = 0; m < 8; m++) {
      int k  = k0 + 32 * m;
      int j  = k & (half - 1);
      int k2 = ((k >> s) << (s + 1)) | j;
      int tk = j << (8 - s);
      float wr = twr[tk];
      float wi = FWD ? twi[tk] : -twi[tk];
      float vr = cr[k2 + half], vi = ci[k2 + half];
      float tr = vr * wr - vi * wi;
      float ti = vr * wi + vi * wr;
      float ur = cr[k2], ui = ci[k2];
      cr[k2] = ur + tr;        ci[k2] = ui + ti;
      cr[k2 + half] = ur - tr; ci[k2 + half] = ui - ti;
    }
  }
  __syncthreads();
}

// forward FFT over 8 contiguous rows per block (real input).
__global__ __launch_bounds__(256) void k_fft_rows(const float* __restrict__ x,
                                                  float2* __restrict__ xf) {
  __shared__ float sr[8 * FSTR], si[8 * FSTR], twr[256], twi[256];
  int t = threadIdx.x;
  int img = blockIdx.x >> 6;
  int r0 = (blockIdx.x & 63) << 3;
  init_tw(twr, twi, t);
  const float4* p4 = (const float4*)(x + (size_t)img * NPIX + (size_t)r0 * 512);
  for (int e = t; e < 1024; e += 256) {
    int row = e >> 7, w = e & 127;
    float4 f = p4[e];
    float* cr = sr + row * FSTR;
    float* ci = si + row * FSTR;
    int p = 4 * w;
    cr[brev9(p)]     = f.x;  ci[brev9(p)]     = 0.0f;
    cr[brev9(p + 1)] = f.y;  ci[brev9(p + 1)] = 0.0f;
    cr[brev9(p + 2)] = f.z;  ci[brev9(p + 2)] = 0.0f;
    cr[brev9(p + 3)] = f.w;  ci[brev9(p + 3)] = 0.0f;
  }
  fft512x8<true>(sr, si, twr, twi, t);
  float4* q4 = (float4*)(xf + (size_t)img * NPIX + (size_t)r0 * 512);
  for (int e = t; e < 2048; e += 256) {
    int row = e >> 8, u = e & 255;
    const float* cr = sr + row * FSTR;
    const float* ci = si + row * FSTR;
    q4[e] = make_float4(cr[2 * u], ci[2 * u], cr[2 * u + 1], ci[2 * u + 1]);
  }
}

// forward FFT over 8 adjacent columns per block (in-place on xf).
__global__ __launch_bounds__(256) void k_fft_cols(float2* __restrict__ xf) {
  __shared__ float sr[8 * FSTR], si[8 * FSTR], twr[256], twi[256];
  int t = threadIdx.x;
  int img = blockIdx.x >> 6;
  int c0 = (blockIdx.x & 63) << 3;
  init_tw(twr, twi, t);
  float2* base = xf + (size_t)img * NPIX + c0;
  for (int e = t; e < 2048; e += 256) {
    int a = e & 31, q = (e >> 5) & 3, b = e >> 7;
    int r = (a << 4) | b;
    float4 f = *(const float4*)(base + (size_t)r * 512 + 2 * q);
    int rr = brev9(r);
    sr[(2 * q) * FSTR + rr]     = f.x;  si[(2 * q) * FSTR + rr]     = f.y;
    sr[(2 * q + 1) * FSTR + rr] = f.z;  si[(2 * q + 1) * FSTR + rr] = f.w;
  }
  fft512x8<true>(sr, si, twr, twi, t);
  for (int e = t; e < 2048; e += 256) {
    int r = e & 511, q = e >> 9;
    float4 f = make_float4(sr[(2 * q) * FSTR + r], si[(2 * q) * FSTR + r],
                           sr[(2 * q + 1) * FSTR + r], si[(2 * q + 1) * FSTR + r]);
    *(float4*)(base + (size_t)r * 512 + 2 * q) = f;
  }
}

// xmag[b][c][h][w] = log10(|xf[(b+4)%8][(c+2)%3][(h+256)%512][(w+256)%512]| + 1)
__global__ __launch_bounds__(256) void k_xmag(const float2* __restrict__ xf,
                                              float* __restrict__ xmag) {
  int idx = blockIdx.x * 256 + threadIdx.x;
  int w = idx & 511;
  int h = (idx >> 9) & 511;
  int bc = idx >> 18;
  int b = bc / 3, c = bc - 3 * b;
  int simg = ((b + 4) & 7) * 3 + ((c + 2) % 3);
  float2 v = xf[(size_t)simg * NPIX + (size_t)((h + 256) & 511) * 512 + ((w + 256) & 511)];
  xmag[idx] = log10f(sqrtf(v.x * v.x + v.y * v.y) + 1.0f);
}

// ---------------------------------------------------------------------------
// Conv stack, occupancy-first: one pre-pool pixel per thread x ALL oc.
// 16x16 pre-pool tile per block, 18x18 staged window per ic (stride 20),
// double-buffered with ONE sync per ic. Pool via shfl_xor(1)/shfl_xor(16).
// ---------------------------------------------------------------------------

// conv1: 6->16, 512x512, pad1, relu, 2x2 avgpool -> [b][16][256][256]
// grid (32, 32, 8)
__global__ __launch_bounds__(256) void k_conv1(const float* __restrict__ x,
                                               const float* __restrict__ xmag,
                                               const float* __restrict__ w1,
                                               const float* __restrict__ b1,
                                               float* __restrict__ out) {
  __shared__ float tile[2][368];
  const int t = threadIdx.x;
  const int tx = t & 15, ty = t >> 4;
  const int bx = blockIdx.x, by = blockIdx.y, b = blockIdx.z;
  const int R0 = by * 16 - 1;
  const int C0 = bx * 16 - 1;

  int li[2], gi[2];
  bool okf[2];
  #pragma unroll
  for (int k = 0; k < 2; k++) {
    int e = t + 256 * k;
    bool valid = e < 324;
    int i = e / 18, j = e - 18 * i;
    int rr = R0 + i, cc = C0 + j;
    bool ok = valid && ((unsigned)rr < 512u) && ((unsigned)cc < 512u);
    li[k] = valid ? (i * 20 + j) : 364;
    gi[k] = ok ? (rr * 512 + cc) : 0;
    okf[k] = ok;
  }

  float acc[16];
  #pragma unroll
  for (int o = 0; o < 16; o++) acc[o] = 0.0f;

  const float* xb = x + (size_t)(b * 3) * NPIX;
  const float* mb = xmag + (size_t)(b * 3) * NPIX;

  float ld[2];
  #pragma unroll
  for (int k = 0; k < 2; k++) ld[k] = okf[k] ? xb[gi[k]] : 0.0f;
  #pragma unroll
  for (int k = 0; k < 2; k++) tile[0][li[k]] = ld[k];
  __syncthreads();

  for (int ic = 0; ic < 6; ic++) {
    if (ic < 5) {
      const float* sn = (ic + 1 < 3) ? (xb + (size_t)(ic + 1) * NPIX)
                                     : (mb + (size_t)(ic - 2) * NPIX);
      #pragma unroll
      for (int k = 0; k < 2; k++) ld[k] = okf[k] ? sn[gi[k]] : 0.0f;
    }
    const float* cur = tile[ic & 1] + ty * 20 + tx;
    float p00 = cur[0],  p01 = cur[1],  p02 = cur[2];
    float p10 = cur[20], p11 = cur[21], p12 = cur[22];
    float p20 = cur[40], p21 = cur[41], p22 = cur[42];
    #pragma unroll
    for (int o = 0; o < 16; o++) {
      const float* wk = w1 + (size_t)(o * 6 + ic) * 9;
      acc[o] += wk[0] * p00 + wk[1] * p01 + wk[2] * p02
              + wk[3] * p10 + wk[4] * p11 + wk[5] * p12
              + wk[6] * p20 + wk[7] * p21 + wk[8] * p22;
    }
    if (ic < 5) {
      float* nxt = tile[(ic + 1) & 1];
      #pragma unroll
      for (int k = 0; k < 2; k++) nxt[li[k]] = ld[k];
      __syncthreads();
    }
  }

  const bool writer = ((tx & 1) == 0) && ((ty & 1) == 0);
  const int pr = by * 8 + (ty >> 1);
  const int pc = bx * 8 + (tx >> 1);
  #pragma unroll
  for (int o = 0; o < 16; o++) {
    float v = fmaxf(acc[o] + b1[o], 0.0f);
    v += __shfl_xor(v, 1);
    v += __shfl_xor(v, 16);
    if (writer) out[((size_t)(b * 16 + o) * 256 + pr) * 256 + pc] = v * 0.25f;
  }
}

// conv2: 16->32, 256x256, pad1, relu, pool. Output reduced to 9 stats per
// (b,oc): T, R0, R127, C0, C127, 4 corners -> S[b][32][9]. grid (16, 16, 8)
__global__ __launch_bounds__(256) void k_conv2(const float* __restrict__ in,
                                               const float* __restrict__ w2,
                                               const float* __restrict__ b2,
                                               float* __restrict__ S) {
  __shared__ float tile[2][368];
  __shared__ float wsum[4][32];
  const int t = threadIdx.x;
  const int tx = t & 15, ty = t >> 4;
  const int bx = blockIdx.x, by = blockIdx.y, b = blockIdx.z;
  const int R0 = by * 16 - 1;
  const int C0 = bx * 16 - 1;

  int li[2], gi[2];
  bool okf[2];
  #pragma unroll
  for (int k = 0; k < 2; k++) {
    int e = t + 256 * k;
    bool valid = e < 324;
    int i = e / 18, j = e - 18 * i;
    int rr = R0 + i, cc = C0 + j;
    bool ok = valid && ((unsigned)rr < 256u) && ((unsigned)cc < 256u);
    li[k] = valid ? (i * 20 + j) : 364;
    gi[k] = ok ? (rr * 256 + cc) : 0;
    okf[k] = ok;
  }

  float acc[32];
  #pragma unroll
  for (int o = 0; o < 32; o++) acc[o] = 0.0f;

  const float* inb = in + (size_t)(b * 16) * 65536;

  float ld[2];
  #pragma unroll
  for (int k = 0; k < 2; k++) ld[k] = okf[k] ? inb[gi[k]] : 0.0f;
  #pragma unroll
  for (int k = 0; k < 2; k++) tile[0][li[k]] = ld[k];
  __syncthreads();

  for (int ic = 0; ic < 16; ic++) {
    if (ic < 15) {
      const float* sn = inb + (size_t)(ic + 1) * 65536;
      #pragma unroll
      for (int k = 0; k < 2; k++) ld[k] = okf[k] ? sn[gi[k]] : 0.0f;
    }
    const float* cur = tile[ic & 1] + ty * 20 + tx;
    float p00 = cur[0],  p01 = cur[1],  p02 = cur[2];
    float p10 = cur[20], p11 = cur[21], p12 = cur[22];
    float p20 = cur[40], p21 = cur[41], p22 = cur[42];
    #pragma unroll
    for (int o = 0; o < 32; o++) {
      const float* wk = w2 + (size_t)(o * 16 + ic) * 9;
      acc[o] += wk[0] * p00 + wk[1] * p01 + wk[2] * p02
              + wk[3] * p10 + wk[4] * p11 + wk[5] * p12
              + wk[6] * p20 + wk[7] * p21 + wk[8] * p22;
    }
    if (ic < 15) {
      float* nxt = tile[(ic + 1) & 1];
      #pragma unroll
      for (int k = 0; k < 2; k++) nxt[li[k]] = ld[k];
      __syncthreads();
    }
  }

  const int lane = t & 63;
  const int wid = t >> 6;
  float* Sb0 = S + (size_t)(b * 32) * 9;
  #pragma unroll
  for (int o = 0; o < 32; o++) {
    float v = fmaxf(acc[o] + b2[o], 0.0f) * 0.25f;   // pre-scaled pooled contribution
    float* Sb = Sb0 + o * 9;
    // total: per-wave reduce -> LDS, combined after loop
    float ts = v;
    #pragma unroll
    for (int off = 32; off > 0; off >>= 1) ts += __shfl_down(ts, off);
    if (lane == 0) wsum[wid][o] = ts;
    // edges (pooled row/col 0 and 127): predicated wave-reduce + 1 atomic
    if (by == 0) {
      float e = (ty < 2) ? v : 0.0f;
      #pragma unroll
      for (int off = 32; off > 0; off >>= 1) e += __shfl_down(e, off);
      if (lane == 0) atomicAdd(&Sb[1], e);
    }
    if (by == 15) {
      float e = (ty >= 14) ? v : 0.0f;
      #pragma unroll
      for (int off = 32; off > 0; off >>= 1) e += __shfl_down(e, off);
      if (lane == 0) atomicAdd(&Sb[2], e);
    }
    if (bx == 0) {
      float e = (tx < 2) ? v : 0.0f;
      #pragma unroll
      for (int off = 32; off > 0; off >>= 1) e += __shfl_down(e, off);
      if (lane == 0) atomicAdd(&Sb[3], e);
    }
    if (bx == 15) {
      float e = (tx >= 14) ? v : 0.0f;
      #pragma unroll
      for (int off = 32; off > 0; off >>= 1) e += __shfl_down(e, off);
      if (lane == 0) atomicAdd(&Sb[4], e);
    }
    // corners (4 pre-pool lanes each)
    if (bx == 0  && by == 0  && ty < 2  && tx < 2)   atomicAdd(&Sb[5], v);
    if (bx == 15 && by == 0  && ty < 2  && tx >= 14) atomicAdd(&Sb[6], v);
    if (bx == 0  && by == 15 && ty >= 14 && tx < 2)  atomicAdd(&Sb[7], v);
    if (bx == 15 && by == 15 && ty >= 14 && tx >= 14) atomicAdd(&Sb[8], v);
  }
  __syncthreads();
  if (t < 32)
    atomicAdd(&Sb0[t * 9], wsum[0][t] + wsum[1][t] + wsum[2][t] + wsum[3][t]);
}

// k_fc: stats -> conv3-mean (matvec over 288 window sums) -> FC1 -> FC2 -> leaky.
__global__ __launch_bounds__(256) void k_fc(const float* __restrict__ S,
                                            const float* __restrict__ w3,
                                            const float* __restrict__ b3,
                                            const float* __restrict__ fw1,
                                            const float* __restrict__ fb1,
                                            const float* __restrict__ fw2,
                                            const float* __restrict__ fb2,
                                            float* __restrict__ vs_out) {
  __shared__ float Sp[2304];   // 8 x 32 x 9 window sums
  __shared__ float y[512];     // 8 x 64
  __shared__ float h1[2048];   // 8 x 256
  int t = threadIdx.x;
  for (int e = t; e < 2304; e += 256) {
    int cell = e / 9, k = e - 9 * cell;
    int dy = k / 3, dx = k - 3 * dy;
    const float* s = S + cell * 9;
    float v = s[0];
    if (dy == 0) v -= s[2];
    if (dy == 2) v -= s[1];
    if (dx == 0) v -= s[4];
    if (dx == 2) v -= s[3];
    if (dy == 0 && dx == 0) v += s[8];
    if (dy == 0 && dx == 2) v += s[7];
    if (dy == 2 && dx == 0) v += s[6];
    if (dy == 2 && dx == 2) v += s[5];
    Sp[e] = v;
  }
  __syncthreads();
  for (int e = t; e < 512; e += 256) {
    int b = e >> 6, o = e & 63;
    const float* wrow = w3 + (size_t)o * 288;
    const float* sp = Sp + b * 288;
    float s = 0.0f;
    #pragma unroll 4
    for (int k = 0; k < 288; k++) s += wrow[k] * sp[k];
    y[e] = b3[o] + s * (1.0f / 16384.0f);
  }
  __syncthreads();
  for (int e = t; e < 2048; e += 256) {
    int b = e >> 8, j = e & 255;
    float s = fb1[j];
    for (int k = 0; k < 64; k++) s += y[b * 64 + k] * fw1[j * 64 + k];
    h1[e] = s;
  }
  __syncthreads();
  for (int e = t; e < 800; e += 256) {
    int b = e / 100, i = e - 100 * b;
    float s = fb2[i];
    for (int j = 0; j < 256; j++) s += h1[b * 256 + j] * fw2[i * 256 + j];
    vs_out[e] = (s >= 0.0f) ? s : 0.01f * s;
  }
}

// fq_mask[b][h][w] = value_set[b][searchsorted(radius_set, dist(h,w), 'left').clip(0,99)]
__global__ __launch_bounds__(256) void k_mask(const float* __restrict__ vs,
                                              float* __restrict__ fq_mask) {
  int idx = blockIdx.x * 256 + threadIdx.x;
  int h = idx >> 9, w = idx & 511;
  float da = (float)h - 256.0f, db = (float)w - 256.0f;
  float dist = sqrtf(da * da + db * db);
  int lo = 0, hi = 100;
  while (lo < hi) {
    int mid = (lo + hi) >> 1;
    float r = (362.03867196751236f * (float)(mid + 1)) * 0.01f;
    if (r < dist) lo = mid + 1; else hi = mid;
  }
  int bin = lo > 99 ? 99 : lo;
  #pragma unroll
  for (int b = 0; b < 8; b++)
    fq_mask[(size_t)b * NPIX + idx] = vs[b * 100 + bin];
}

// inverse FFT over 8 rows per block, spectrum modulation fused on load.
__global__ __launch_bounds__(256) void k_ifft_rows_mod(float2* __restrict__ xf,
                                                       const float* __restrict__ fq_mask) {
  __shared__ float sr[8 * FSTR], si[8 * FSTR], twr[256], twi[256];
  int t = threadIdx.x;
  int img = blockIdx.x >> 6;
  int r0 = (blockIdx.x & 63) << 3;
  int bm = ((img / 3) + 4) & 7;
  init_tw(twr, twi, t);
  const float* mbase = fq_mask + (size_t)bm * NPIX;
  float4* base4 = (float4*)(xf + (size_t)img * NPIX + (size_t)r0 * 512);
  for (int e = t; e < 2048; e += 256) {
    int u = (e & 3) | (((e >> 2) & 15) << 3) | (((e >> 6) & 1) << 2) | (((e >> 7) & 1) << 7);
    int row = e >> 8;
    float4 f = base4[row * 256 + u];
    int p0 = 2 * u;
    const float* mrow = mbase + (size_t)((r0 + row + 256) & 511) * 512;
    float2 m = *(const float2*)(mrow + ((p0 + 256) & 511));
    int rr0 = brev9(p0);
    float* cr = sr + row * FSTR;
    float* ci = si + row * FSTR;
    cr[rr0]       = f.x * m.x;  ci[rr0]       = f.y * m.x;
    cr[rr0 + 256] = f.z * m.y;  ci[rr0 + 256] = f.w * m.y;
  }
  fft512x8<false>(sr, si, twr, twi, t);
  for (int e = t; e < 2048; e += 256) {
    int row = e >> 8, u = e & 255;
    const float* cr = sr + row * FSTR;
    const float* ci = si + row * FSTR;
    base4[e] = make_float4(cr[2 * u], ci[2 * u], cr[2 * u + 1], ci[2 * u + 1]);
  }
}

// inverse FFT over 8 columns per block, scale 1/N, clip -> lowpass.
__global__ __launch_bounds__(256) void k_ifft_cols_out(const float2* __restrict__ xf,
                                                       float* __restrict__ lowpass) {
  __shared__ float sr[8 * FSTR], si[8 * FSTR], twr[256], twi[256];
  int t = threadIdx.x;
  int img = blockIdx.x >> 6;
  int c0 = (blockIdx.x & 63) << 3;
  init_tw(twr, twi, t);
  const float2* base = xf + (size_t)img * NPIX + c0;
  for (int e = t; e < 2048; e += 256) {
    int a = e & 31, q = (e >> 5) & 3, b = e >> 7;
    int r = (a << 4) | b;
    float4 f = *(const float4*)(base + (size_t)r * 512 + 2 * q);
    int rr = brev9(r);
    sr[(2 * q) * FSTR + rr]     = f.x;  si[(2 * q) * FSTR + rr]     = f.y;
    sr[(2 * q + 1) * FSTR + rr] = f.z;  si[(2 * q + 1) * FSTR + rr] = f.w;
  }
  fft512x8<false>(sr, si, twr, twi, t);
  const float sc = 1.0f / 262144.0f;
  float* obase = lowpass + (size_t)img * NPIX + c0;
  for (int e = t; e < 2048; e += 256) {
    int r = e & 511, q = e >> 9;
    float v0 = fminf(fmaxf(sr[(2 * q) * FSTR + r] * sc, 0.0f), 1.0f);
    float v1 = fminf(fmaxf(sr[(2 * q + 1) * FSTR + r] * sc, 0.0f), 1.0f);
    *(float2*)(obase + (size_t)r * 512 + 2 * q) = make_float2(v0, v1);
  }
}

extern "C" void kernel_launch(void* const* d_in, const int* in_sizes, int n_in,
                              void* d_out, int out_size, void* d_ws, size_t ws_size,
                              hipStream_t stream) {
  const float* x   = (const float*)d_in[0];
  const float* w1  = (const float*)d_in[1];
  const float* b1  = (const float*)d_in[2];
  const float* w2  = (const float*)d_in[3];
  const float* b2  = (const float*)d_in[4];
  const float* w3  = (const float*)d_in[5];
  const float* b3  = (const float*)d_in[6];
  const float* fw1 = (const float*)d_in[7];
  const float* fb1 = (const float*)d_in[8];
  const float* fw2 = (const float*)d_in[9];
  const float* fb2 = (const float*)d_in[10];

  float* lowpass = (float*)d_out;            // 8*3*512*512
  float* fq_mask = lowpass + 6291456;        // 8*512*512
  float* vs      = fq_mask + 2097152;        // 8*100

  float* base    = (float*)d_ws;
  float2* xf     = (float2*)base;            // 12582912 floats
  float* xmag    = base + 12582912;          // 6291456 floats
  float* pooled1 = xmag + 6291456;           // 8388608 floats
  float* S       = pooled1 + 8388608;        // 8*32*9 = 2304 floats

  k_fft_rows<<<dim3(24 * 64), 256, 0, stream>>>(x, xf);
  k_fft_cols<<<dim3(24 * 64), 256, 0, stream>>>(xf);

  k_xmag<<<6291456 / 256, 256, 0, stream>>>(xf, xmag);

  k_conv1<<<dim3(32, 32, 8), 256, 0, stream>>>(x, xmag, w1, b1, pooled1);
  hipMemsetAsync(S, 0, 2304 * sizeof(float), stream);
  k_conv2<<<dim3(16, 16, 8), 256, 0, stream>>>(pooled1, w2, b2, S);

  k_fc<<<1, 256, 0, stream>>>(S, w3, b3, fw1, fb1, fw2, fb2, vs);
  k_mask<<<1024, 256, 0, stream>>>(vs, fq_mask);

  k_ifft_rows_mod<<<dim3(24 * 64), 256, 0, stream>>>(xf, fq_mask);
  k_ifft_cols_out<<<dim3(24 * 64), 256, 0, stream>>>(xf, lowpass);
}

// Round 7
// 472.790 us; speedup vs baseline: 1.5945x; 1.5945x over previous
//
#include <hip/hip_runtime.h>
#include <math.h>

#define NPIX 262144   // 512*512
#define FSTR 513      // LDS column stride for batch-8 FFT (pad 512+1)

__device__ __forceinline__ int brev9(int i) { return (int)(__brev((unsigned)i) >> 23); }

__device__ __forceinline__ void init_tw(float* twr, float* twi, int t) {
  if (t < 256) {
    float ang = -3.14159265358979323846f * (float)t / 256.0f;
    float s, c;
    sincosf(ang, &s, &c);
    twr[t] = c; twi[t] = s;
  }
}

// 8 x 512-pt radix-2 DIT FFTs in LDS, column-major: element p of FFT c at
// [c*FSTR + p]. 256 threads: c = t>>5, 32 threads x 8 butterflies/stage/FFT.
template<bool FWD>
__device__ __forceinline__ void fft512x8(float* __restrict__ sr, float* __restrict__ si,
                                         const float* __restrict__ twr,
                                         const float* __restrict__ twi, int t) {
  const int c  = t >> 5;
  const int k0 = t & 31;
  float* cr = sr + c * FSTR;
  float* ci = si + c * FSTR;
  #pragma unroll
  for (int s = 0; s < 9; s++) {
    const int half = 1 << s;
    __syncthreads();
    #pragma unroll
    for (int m = 0; m < 8; m++) {
      int k  = k0 + 32 * m;
      int j  = k & (half - 1);
      int k2 = ((k >> s) << (s + 1)) | j;
      int tk = j << (8 - s);
      float wr = twr[tk];
      float wi = FWD ? twi[tk] : -twi[tk];
      float vr = cr[k2 + half], vi = ci[k2 + half];
      float tr = vr * wr - vi * wi;
      float ti = vr * wi + vi * wr;
      float ur = cr[k2], ui = ci[k2];
      cr[k2] = ur + tr;        ci[k2] = ui + ti;
      cr[k2 + half] = ur - tr; ci[k2 + half] = ui - ti;
    }
  }
  __syncthreads();
}

// forward FFT over 8 contiguous rows per block (real input).
__global__ __launch_bounds__(256) void k_fft_rows(const float* __restrict__ x,
                                                  float2* __restrict__ xf) {
  __shared__ float sr[8 * FSTR], si[8 * FSTR], twr[256], twi[256];
  int t = threadIdx.x;
  int img = blockIdx.x >> 6;
  int r0 = (blockIdx.x & 63) << 3;
  init_tw(twr, twi, t);
  const float4* p4 = (const float4*)(x + (size_t)img * NPIX + (size_t)r0 * 512);
  for (int e = t; e < 1024; e += 256) {
    int row = e >> 7, w = e & 127;
    float4 f = p4[e];
    float* cr = sr + row * FSTR;
    float* ci = si + row * FSTR;
    int p = 4 * w;
    cr[brev9(p)]     = f.x;  ci[brev9(p)]     = 0.0f;
    cr[brev9(p + 1)] = f.y;  ci[brev9(p + 1)] = 0.0f;
    cr[brev9(p + 2)] = f.z;  ci[brev9(p + 2)] = 0.0f;
    cr[brev9(p + 3)] = f.w;  ci[brev9(p + 3)] = 0.0f;
  }
  fft512x8<true>(sr, si, twr, twi, t);
  float4* q4 = (float4*)(xf + (size_t)img * NPIX + (size_t)r0 * 512);
  for (int e = t; e < 2048; e += 256) {
    int row = e >> 8, u = e & 255;
    const float* cr = sr + row * FSTR;
    const float* ci = si + row * FSTR;
    q4[e] = make_float4(cr[2 * u], ci[2 * u], cr[2 * u + 1], ci[2 * u + 1]);
  }
}

// forward FFT over 8 adjacent columns per block (in-place on xf), with the
// log-magnitude (xmag) output fused: the epilogue already holds the full 2D
// spectrum for these 8 columns, so it also writes
// xmag[b][c][h][w] = log10(|xf[simg][(h+256)&511][(w+256)&511]|+1)
// where simg=((b+4)&7)*3+((c+2)%3)  ->  inverse: b=(sb+4)&7, c=(sc+1)%3.
__global__ __launch_bounds__(256) void k_fft_cols(float2* __restrict__ xf,
                                                  float* __restrict__ xmag) {
  __shared__ float sr[8 * FSTR], si[8 * FSTR], twr[256], twi[256];
  int t = threadIdx.x;
  int img = blockIdx.x >> 6;
  int c0 = (blockIdx.x & 63) << 3;
  init_tw(twr, twi, t);
  float2* base = xf + (size_t)img * NPIX + c0;
  for (int e = t; e < 2048; e += 256) {
    int a = e & 31, q = (e >> 5) & 3, b = e >> 7;
    int r = (a << 4) | b;
    float4 f = *(const float4*)(base + (size_t)r * 512 + 2 * q);
    int rr = brev9(r);
    sr[(2 * q) * FSTR + rr]     = f.x;  si[(2 * q) * FSTR + rr]     = f.y;
    sr[(2 * q + 1) * FSTR + rr] = f.z;  si[(2 * q + 1) * FSTR + rr] = f.w;
  }
  fft512x8<true>(sr, si, twr, twi, t);
  int sb = img / 3, sc = img - 3 * sb;
  int dimg = ((sb + 4) & 7) * 3 + (sc + 1) % 3;
  float* xb = xmag + (size_t)dimg * NPIX + (c0 ^ 256);
  for (int e = t; e < 2048; e += 256) {
    int r = e & 511, q = e >> 9;
    float a0 = sr[(2 * q) * FSTR + r],     b0 = si[(2 * q) * FSTR + r];
    float a1 = sr[(2 * q + 1) * FSTR + r], b1 = si[(2 * q + 1) * FSTR + r];
    *(float4*)(base + (size_t)r * 512 + 2 * q) = make_float4(a0, b0, a1, b1);
    float m0 = log10f(sqrtf(a0 * a0 + b0 * b0) + 1.0f);
    float m1 = log10f(sqrtf(a1 * a1 + b1 * b1) + 1.0f);
    *(float2*)(xb + (size_t)(r ^ 256) * 512 + 2 * q) = make_float2(m0, m1);
  }
}

// conv1: 6->16, 512x512, pad1, relu, 2x2 avgpool -> [b][16][256][256]
// grid (4, 32, 16). Double-buffered LDS staging, 1 ic per round. (round-5 proven)
__global__ __launch_bounds__(256) void k_conv1(const float* __restrict__ x,
                                               const float* __restrict__ xmag,
                                               const float* __restrict__ w1,
                                               const float* __restrict__ b1,
                                               float* __restrict__ out) {
  __shared__ float tile[2][18 * 132 + 8];
  const int t = threadIdx.x;
  const int tx = t & 31, ty = t >> 5;
  const int PC0 = blockIdx.x * 64;
  const int PR0 = blockIdx.y * 8;
  const int b  = blockIdx.z >> 1;
  const int og = (blockIdx.z & 1) * 8;
  const int R0 = PR0 * 2 - 1;
  const int C0 = PC0 * 2 - 1;

  int li[10], gi[10];
  bool okf[10];
  #pragma unroll
  for (int k = 0; k < 10; k++) {
    int e = t + 256 * k;
    bool valid = e < 2340;
    int i = e / 130, j = e - i * 130;
    int rr = R0 + i, cc = C0 + j;
    bool ok = valid && ((unsigned)rr < 512u) && ((unsigned)cc < 512u);
    li[k] = valid ? (i * 132 + j) : (18 * 132);
    gi[k] = ok ? (rr * 512 + cc) : 0;
    okf[k] = ok;
  }

  float acc[8][8];
  #pragma unroll
  for (int o = 0; o < 8; o++)
    #pragma unroll
    for (int q = 0; q < 8; q++) acc[o][q] = 0.0f;

  const float* xb = x + (size_t)(b * 3) * NPIX;
  const float* mb = xmag + (size_t)(b * 3) * NPIX;

  float ld[10];
  #pragma unroll
  for (int k = 0; k < 10; k++) ld[k] = okf[k] ? xb[gi[k]] : 0.0f;
  #pragma unroll
  for (int k = 0; k < 10; k++) tile[0][li[k]] = ld[k];
  __syncthreads();

  for (int ic = 0; ic < 6; ic++) {
    if (ic < 5) {
      const float* sn = (ic + 1 < 3) ? (xb + (size_t)(ic + 1) * NPIX)
                                     : (mb + (size_t)(ic - 2) * NPIX);
      #pragma unroll
      for (int k = 0; k < 10; k++) ld[k] = okf[k] ? sn[gi[k]] : 0.0f;
    }
    const float* cur = tile[ic & 1];
    float patch[4][6];
    #pragma unroll
    for (int dy = 0; dy < 4; dy++) {
      const float* rp = cur + (2 * ty + dy) * 132 + 4 * tx;
      float4 f = *(const float4*)rp;
      float2 g = *(const float2*)(rp + 4);
      patch[dy][0] = f.x; patch[dy][1] = f.y; patch[dy][2] = f.z;
      patch[dy][3] = f.w; patch[dy][4] = g.x; patch[dy][5] = g.y;
    }
    #pragma unroll
    for (int o = 0; o < 8; o++) {
      const float* wk = w1 + (size_t)((og + o) * 6 + ic) * 9;
      float k0 = wk[0], k1 = wk[1], k2 = wk[2], k3 = wk[3], k4 = wk[4],
            k5 = wk[5], k6 = wk[6], k7 = wk[7], k8 = wk[8];
      #pragma unroll
      for (int py = 0; py < 2; py++)
        #pragma unroll
        for (int px = 0; px < 4; px++) {
          acc[o][py * 4 + px] +=
              k0 * patch[py][px]     + k1 * patch[py][px + 1]     + k2 * patch[py][px + 2]
            + k3 * patch[py + 1][px] + k4 * patch[py + 1][px + 1] + k5 * patch[py + 1][px + 2]
            + k6 * patch[py + 2][px] + k7 * patch[py + 2][px + 1] + k8 * patch[py + 2][px + 2];
        }
    }
    if (ic < 5) {
      __syncthreads();
      float* nxt = tile[(ic + 1) & 1];
      #pragma unroll
      for (int k = 0; k < 10; k++) nxt[li[k]] = ld[k];
      __syncthreads();
    }
  }
  #pragma unroll
  for (int o = 0; o < 8; o++) {
    float bias = b1[og + o];
    float p0 = fmaxf(acc[o][0] + bias, 0.0f) + fmaxf(acc[o][1] + bias, 0.0f)
             + fmaxf(acc[o][4] + bias, 0.0f) + fmaxf(acc[o][5] + bias, 0.0f);
    float p1 = fmaxf(acc[o][2] + bias, 0.0f) + fmaxf(acc[o][3] + bias, 0.0f)
             + fmaxf(acc[o][6] + bias, 0.0f) + fmaxf(acc[o][7] + bias, 0.0f);
    float2* q = (float2*)(out + ((size_t)(b * 16 + og + o) * 256 + PR0 + ty) * 256 + PC0 + 2 * tx);
    *q = make_float2(p0 * 0.25f, p1 * 0.25f);
  }
}

// conv2: 16->32, 256x256, pad1, relu, pool. Output reduced to 9 stats per
// (b,oc): T, R0, R127, C0, C127, 4 corners -> S[b][32][9].
// grid (4, 16, 32) = 2048 blocks (8/CU). Thread: 1 pooled col x 8 oc.
// Tile 18x66 (stride 68), double-buffered, 1 ic per round.
__global__ __launch_bounds__(256) void k_conv2(const float* __restrict__ in,
                                               const float* __restrict__ w2,
                                               const float* __restrict__ b2,
                                               float* __restrict__ S) {
  __shared__ float tile[2][18 * 68 + 8];
  __shared__ float wsum[4][8];
  const int t = threadIdx.x;
  const int tx = t & 31, ty = t >> 5;
  const int bx = blockIdx.x, by = blockIdx.y;
  const int PC0 = bx * 32;
  const int PR0 = by * 8;
  const int b  = blockIdx.z >> 2;
  const int og = (blockIdx.z & 3) * 8;
  const int R0 = PR0 * 2 - 1;
  const int C0 = PC0 * 2 - 1;

  int li[5], gi[5];
  bool okf[5];
  #pragma unroll
  for (int k = 0; k < 5; k++) {
    int e = t + 256 * k;
    bool valid = e < 1188;            // 18 rows x 66 cols
    int i = e / 66, j = e - 66 * i;
    int rr = R0 + i, cc = C0 + j;
    bool ok = valid && ((unsigned)rr < 256u) && ((unsigned)cc < 256u);
    li[k] = valid ? (i * 68 + j) : (18 * 68);
    gi[k] = ok ? (rr * 256 + cc) : 0;
    okf[k] = ok;
  }

  float acc[8][4];
  #pragma unroll
  for (int o = 0; o < 8; o++)
    #pragma unroll
    for (int q = 0; q < 4; q++) acc[o][q] = 0.0f;

  const float* inb = in + (size_t)(b * 16) * 65536;

  float ld[5];
  #pragma unroll
  for (int k = 0; k < 5; k++) ld[k] = okf[k] ? inb[gi[k]] : 0.0f;
  #pragma unroll
  for (int k = 0; k < 5; k++) tile[0][li[k]] = ld[k];
  __syncthreads();

  for (int ic = 0; ic < 16; ic++) {
    if (ic < 15) {
      const float* sn = inb + (size_t)(ic + 1) * 65536;
      #pragma unroll
      for (int k = 0; k < 5; k++) ld[k] = okf[k] ? sn[gi[k]] : 0.0f;
    }
    const float* cur = tile[ic & 1];
    float patch[4][4];
    #pragma unroll
    for (int dy = 0; dy < 4; dy++) {
      const float* rp = cur + (2 * ty + dy) * 68 + 2 * tx;
      float2 f0 = *(const float2*)rp;
      float2 f1 = *(const float2*)(rp + 2);
      patch[dy][0] = f0.x; patch[dy][1] = f0.y;
      patch[dy][2] = f1.x; patch[dy][3] = f1.y;
    }
    #pragma unroll
    for (int o = 0; o < 8; o++) {
      const float* wk = w2 + (size_t)((og + o) * 16 + ic) * 9;
      float k0 = wk[0], k1 = wk[1], k2 = wk[2], k3 = wk[3], k4 = wk[4],
            k5 = wk[5], k6 = wk[6], k7 = wk[7], k8 = wk[8];
      #pragma unroll
      for (int py = 0; py < 2; py++)
        #pragma unroll
        for (int px = 0; px < 2; px++) {
          acc[o][py * 2 + px] +=
              k0 * patch[py][px]     + k1 * patch[py][px + 1]     + k2 * patch[py][px + 2]
            + k3 * patch[py + 1][px] + k4 * patch[py + 1][px + 1] + k5 * patch[py + 1][px + 2]
            + k6 * patch[py + 2][px] + k7 * patch[py + 2][px + 1] + k8 * patch[py + 2][px + 2];
        }
    }
    if (ic < 15) {
      __syncthreads();
      float* nxt = tile[(ic + 1) & 1];
      #pragma unroll
      for (int k = 0; k < 5; k++) nxt[li[k]] = ld[k];
      __syncthreads();
    }
  }

  const int lane = t & 63;
  const int wid = t >> 6;
  float* Sb0 = S + (size_t)(b * 32 + og) * 9;
  #pragma unroll
  for (int o = 0; o < 8; o++) {
    float bias = b2[og + o];
    float v = (fmaxf(acc[o][0] + bias, 0.0f) + fmaxf(acc[o][1] + bias, 0.0f)
             + fmaxf(acc[o][2] + bias, 0.0f) + fmaxf(acc[o][3] + bias, 0.0f)) * 0.25f;
    float* Sb = Sb0 + o * 9;
    float ts = v;
    #pragma unroll
    for (int off = 32; off > 0; off >>= 1) ts += __shfl_down(ts, off);
    if (lane == 0) wsum[wid][o] = ts;
    if (by == 0) {
      float e = (ty == 0) ? v : 0.0f;
      #pragma unroll
      for (int off = 32; off > 0; off >>= 1) e += __shfl_down(e, off);
      if (lane == 0) atomicAdd(&Sb[1], e);
    }
    if (by == 15) {
      float e = (ty == 7) ? v : 0.0f;
      #pragma unroll
      for (int off = 32; off > 0; off >>= 1) e += __shfl_down(e, off);
      if (lane == 0) atomicAdd(&Sb[2], e);
    }
    if (bx == 0 && tx == 0)  atomicAdd(&Sb[3], v);
    if (bx == 3 && tx == 31) atomicAdd(&Sb[4], v);
    if (bx == 0 && by == 0  && t == 0)   Sb[5] = v;
    if (bx == 3 && by == 0  && t == 31)  Sb[6] = v;
    if (bx == 0 && by == 15 && t == 224) Sb[7] = v;
    if (bx == 3 && by == 15 && t == 255) Sb[8] = v;
  }
  __syncthreads();
  if (t < 8)
    atomicAdd(&Sb0[t * 9], wsum[0][t] + wsum[1][t] + wsum[2][t] + wsum[3][t]);
}

// k_fc: stats -> conv3-mean (matvec over 288 window sums) -> FC1 -> FC2 -> leaky.
__global__ __launch_bounds__(256) void k_fc(const float* __restrict__ S,
                                            const float* __restrict__ w3,
                                            const float* __restrict__ b3,
                                            const float* __restrict__ fw1,
                                            const float* __restrict__ fb1,
                                            const float* __restrict__ fw2,
                                            const float* __restrict__ fb2,
                                            float* __restrict__ vs_out) {
  __shared__ float Sp[2304];   // 8 x 32 x 9 window sums
  __shared__ float y[512];     // 8 x 64
  __shared__ float h1[2048];   // 8 x 256
  int t = threadIdx.x;
  for (int e = t; e < 2304; e += 256) {
    int cell = e / 9, k = e - 9 * cell;
    int dy = k / 3, dx = k - 3 * dy;
    const float* s = S + cell * 9;
    float v = s[0];
    if (dy == 0) v -= s[2];
    if (dy == 2) v -= s[1];
    if (dx == 0) v -= s[4];
    if (dx == 2) v -= s[3];
    if (dy == 0 && dx == 0) v += s[8];
    if (dy == 0 && dx == 2) v += s[7];
    if (dy == 2 && dx == 0) v += s[6];
    if (dy == 2 && dx == 2) v += s[5];
    Sp[e] = v;
  }
  __syncthreads();
  for (int e = t; e < 512; e += 256) {
    int b = e >> 6, o = e & 63;
    const float* wrow = w3 + (size_t)o * 288;
    const float* sp = Sp + b * 288;
    float s = 0.0f;
    #pragma unroll 4
    for (int k = 0; k < 288; k++) s += wrow[k] * sp[k];
    y[e] = b3[o] + s * (1.0f / 16384.0f);
  }
  __syncthreads();
  for (int e = t; e < 2048; e += 256) {
    int b = e >> 8, j = e & 255;
    float s = fb1[j];
    for (int k = 0; k < 64; k++) s += y[b * 64 + k] * fw1[j * 64 + k];
    h1[e] = s;
  }
  __syncthreads();
  for (int e = t; e < 800; e += 256) {
    int b = e / 100, i = e - 100 * b;
    float s = fb2[i];
    for (int j = 0; j < 256; j++) s += h1[b * 256 + j] * fw2[i * 256 + j];
    vs_out[e] = (s >= 0.0f) ? s : 0.01f * s;
  }
}

// fq_mask[b][h][w] = value_set[b][searchsorted(radius_set, dist(h,w), 'left').clip(0,99)]
__global__ __launch_bounds__(256) void k_mask(const float* __restrict__ vs,
                                              float* __restrict__ fq_mask) {
  int idx = blockIdx.x * 256 + threadIdx.x;
  int h = idx >> 9, w = idx & 511;
  float da = (float)h - 256.0f, db = (float)w - 256.0f;
  float dist = sqrtf(da * da + db * db);
  int lo = 0, hi = 100;
  while (lo < hi) {
    int mid = (lo + hi) >> 1;
    float r = (362.03867196751236f * (float)(mid + 1)) * 0.01f;
    if (r < dist) lo = mid + 1; else hi = mid;
  }
  int bin = lo > 99 ? 99 : lo;
  #pragma unroll
  for (int b = 0; b < 8; b++)
    fq_mask[(size_t)b * NPIX + idx] = vs[b * 100 + bin];
}

// inverse FFT over 8 rows per block, spectrum modulation fused on load.
__global__ __launch_bounds__(256) void k_ifft_rows_mod(float2* __restrict__ xf,
                                                       const float* __restrict__ fq_mask) {
  __shared__ float sr[8 * FSTR], si[8 * FSTR], twr[256], twi[256];
  int t = threadIdx.x;
  int img = blockIdx.x >> 6;
  int r0 = (blockIdx.x & 63) << 3;
  int bm = ((img / 3) + 4) & 7;
  init_tw(twr, twi, t);
  const float* mbase = fq_mask + (size_t)bm * NPIX;
  float4* base4 = (float4*)(xf + (size_t)img * NPIX + (size_t)r0 * 512);
  for (int e = t; e < 2048; e += 256) {
    int u = (e & 3) | (((e >> 2) & 15) << 3) | (((e >> 6) & 1) << 2) | (((e >> 7) & 1) << 7);
    int row = e >> 8;
    float4 f = base4[row * 256 + u];
    int p0 = 2 * u;
    const float* mrow = mbase + (size_t)((r0 + row + 256) & 511) * 512;
    float2 m = *(const float2*)(mrow + ((p0 + 256) & 511));
    int rr0 = brev9(p0);
    float* cr = sr + row * FSTR;
    float* ci = si + row * FSTR;
    cr[rr0]       = f.x * m.x;  ci[rr0]       = f.y * m.x;
    cr[rr0 + 256] = f.z * m.y;  ci[rr0 + 256] = f.w * m.y;
  }
  fft512x8<false>(sr, si, twr, twi, t);
  for (int e = t; e < 2048; e += 256) {
    int row = e >> 8, u = e & 255;
    const float* cr = sr + row * FSTR;
    const float* ci = si + row * FSTR;
    base4[e] = make_float4(cr[2 * u], ci[2 * u], cr[2 * u + 1], ci[2 * u + 1]);
  }
}

// inverse FFT over 8 columns per block, scale 1/N, clip -> lowpass.
__global__ __launch_bounds__(256) void k_ifft_cols_out(const float2* __restrict__ xf,
                                                       float* __restrict__ lowpass) {
  __shared__ float sr[8 * FSTR], si[8 * FSTR], twr[256], twi[256];
  int t = threadIdx.x;
  int img = blockIdx.x >> 6;
  int c0 = (blockIdx.x & 63) << 3;
  init_tw(twr, twi, t);
  const float2* base = xf + (size_t)img * NPIX + c0;
  for (int e = t; e < 2048; e += 256) {
    int a = e & 31, q = (e >> 5) & 3, b = e >> 7;
    int r = (a << 4) | b;
    float4 f = *(const float4*)(base + (size_t)r * 512 + 2 * q);
    int rr = brev9(r);
    sr[(2 * q) * FSTR + rr]     = f.x;  si[(2 * q) * FSTR + rr]     = f.y;
    sr[(2 * q + 1) * FSTR + rr] = f.z;  si[(2 * q + 1) * FSTR + rr] = f.w;
  }
  fft512x8<false>(sr, si, twr, twi, t);
  const float sc = 1.0f / 262144.0f;
  float* obase = lowpass + (size_t)img * NPIX + c0;
  for (int e = t; e < 2048; e += 256) {
    int r = e & 511, q = e >> 9;
    float v0 = fminf(fmaxf(sr[(2 * q) * FSTR + r] * sc, 0.0f), 1.0f);
    float v1 = fminf(fmaxf(sr[(2 * q + 1) * FSTR + r] * sc, 0.0f), 1.0f);
    *(float2*)(obase + (size_t)r * 512 + 2 * q) = make_float2(v0, v1);
  }
}

extern "C" void kernel_launch(void* const* d_in, const int* in_sizes, int n_in,
                              void* d_out, int out_size, void* d_ws, size_t ws_size,
                              hipStream_t stream) {
  const float* x   = (const float*)d_in[0];
  const float* w1  = (const float*)d_in[1];
  const float* b1  = (const float*)d_in[2];
  const float* w2  = (const float*)d_in[3];
  const float* b2  = (const float*)d_in[4];
  const float* w3  = (const float*)d_in[5];
  const float* b3  = (const float*)d_in[6];
  const float* fw1 = (const float*)d_in[7];
  const float* fb1 = (const float*)d_in[8];
  const float* fw2 = (const float*)d_in[9];
  const float* fb2 = (const float*)d_in[10];

  float* lowpass = (float*)d_out;            // 8*3*512*512
  float* fq_mask = lowpass + 6291456;        // 8*512*512
  float* vs      = fq_mask + 2097152;        // 8*100

  float* base    = (float*)d_ws;
  float2* xf     = (float2*)base;            // 12582912 floats
  float* xmag    = base + 12582912;          // 6291456 floats
  float* pooled1 = xmag + 6291456;           // 8388608 floats
  float* S       = pooled1 + 8388608;        // 8*32*9 = 2304 floats

  k_fft_rows<<<dim3(24 * 64), 256, 0, stream>>>(x, xf);
  k_fft_cols<<<dim3(24 * 64), 256, 0, stream>>>(xf, xmag);   // xmag fused

  k_conv1<<<dim3(4, 32, 16), 256, 0, stream>>>(x, xmag, w1, b1, pooled1);
  hipMemsetAsync(S, 0, 2304 * sizeof(float), stream);
  k_conv2<<<dim3(4, 16, 32), 256, 0, stream>>>(pooled1, w2, b2, S);

  k_fc<<<1, 256, 0, stream>>>(S, w3, b3, fw1, fb1, fw2, fb2, vs);
  k_mask<<<1024, 256, 0, stream>>>(vs, fq_mask);

  k_ifft_rows_mod<<<dim3(24 * 64), 256, 0, stream>>>(xf, fq_mask);
  k_ifft_cols_out<<<dim3(24 * 64), 256, 0, stream>>>(xf, lowpass);
}

// Round 8
// 410.436 us; speedup vs baseline: 1.8367x; 1.1519x over previous
//
#include <hip/hip_runtime.h>
#include <math.h>

#define NPIX 262144   // 512*512
#define FSTR 513      // LDS column stride for batch-8 FFT (pad 512+1)

__device__ __forceinline__ int brev9(int i) { return (int)(__brev((unsigned)i) >> 23); }

__device__ __forceinline__ void init_tw(float* twr, float* twi, int t) {
  if (t < 256) {
    float ang = -3.14159265358979323846f * (float)t / 256.0f;
    float s, c;
    sincosf(ang, &s, &c);
    twr[t] = c; twi[t] = s;
  }
}

// 8 x 512-pt radix-2 DIT FFTs in LDS, column-major: element p of FFT c at
// [c*FSTR + p]. 256 threads: c = t>>5, 32 threads x 8 butterflies/stage/FFT.
template<bool FWD>
__device__ __forceinline__ void fft512x8(float* __restrict__ sr, float* __restrict__ si,
                                         const float* __restrict__ twr,
                                         const float* __restrict__ twi, int t) {
  const int c  = t >> 5;
  const int k0 = t & 31;
  float* cr = sr + c * FSTR;
  float* ci = si + c * FSTR;
  #pragma unroll
  for (int s = 0; s < 9; s++) {
    const int half = 1 << s;
    __syncthreads();
    #pragma unroll
    for (int m = 0; m < 8; m++) {
      int k  = k0 + 32 * m;
      int j  = k & (half - 1);
      int k2 = ((k >> s) << (s + 1)) | j;
      int tk = j << (8 - s);
      float wr = twr[tk];
      float wi = FWD ? twi[tk] : -twi[tk];
      float vr = cr[k2 + half], vi = ci[k2 + half];
      float tr = vr * wr - vi * wi;
      float ti = vr * wi + vi * wr;
      float ur = cr[k2], ui = ci[k2];
      cr[k2] = ur + tr;        ci[k2] = ui + ti;
      cr[k2 + half] = ur - tr; ci[k2 + half] = ui - ti;
    }
  }
  __syncthreads();
}

// forward FFT over 8 contiguous rows per block (real input).
__global__ __launch_bounds__(256) void k_fft_rows(const float* __restrict__ x,
                                                  float2* __restrict__ xf) {
  __shared__ float sr[8 * FSTR], si[8 * FSTR], twr[256], twi[256];
  int t = threadIdx.x;
  int img = blockIdx.x >> 6;
  int r0 = (blockIdx.x & 63) << 3;
  init_tw(twr, twi, t);
  const float4* p4 = (const float4*)(x + (size_t)img * NPIX + (size_t)r0 * 512);
  for (int e = t; e < 1024; e += 256) {
    int row = e >> 7, w = e & 127;
    float4 f = p4[e];
    float* cr = sr + row * FSTR;
    float* ci = si + row * FSTR;
    int p = 4 * w;
    cr[brev9(p)]     = f.x;  ci[brev9(p)]     = 0.0f;
    cr[brev9(p + 1)] = f.y;  ci[brev9(p + 1)] = 0.0f;
    cr[brev9(p + 2)] = f.z;  ci[brev9(p + 2)] = 0.0f;
    cr[brev9(p + 3)] = f.w;  ci[brev9(p + 3)] = 0.0f;
  }
  fft512x8<true>(sr, si, twr, twi, t);
  float4* q4 = (float4*)(xf + (size_t)img * NPIX + (size_t)r0 * 512);
  for (int e = t; e < 2048; e += 256) {
    int row = e >> 8, u = e & 255;
    const float* cr = sr + row * FSTR;
    const float* ci = si + row * FSTR;
    q4[e] = make_float4(cr[2 * u], ci[2 * u], cr[2 * u + 1], ci[2 * u + 1]);
  }
}

// forward FFT over 8 adjacent columns per block (in-place on xf), xmag fused.
// Lane map packs global txns: q=t&3 -> 4 lanes cover one 64B row (16 txn/instr).
// Load rows stride-32 (spreads brev9 LDS banks: 2-way); store rows consecutive.
__global__ __launch_bounds__(256) void k_fft_cols(float2* __restrict__ xf,
                                                  float* __restrict__ xmag) {
  __shared__ float sr[8 * FSTR], si[8 * FSTR], twr[256], twi[256];
  int t = threadIdx.x;
  int img = blockIdx.x >> 6;
  int c0 = (blockIdx.x & 63) << 3;
  init_tw(twr, twi, t);
  float2* base = xf + (size_t)img * NPIX + c0;
  const int q = t & 3;
  const int j = (t >> 2) & 15;
  const int w = t >> 6;
  #pragma unroll
  for (int it = 0; it < 8; it++) {
    int row = 32 * j + 4 * it + w;           // stride-32 row set
    float4 f = *(const float4*)(base + (size_t)row * 512 + 2 * q);
    int rr = brev9(row);
    sr[(2 * q) * FSTR + rr]     = f.x;  si[(2 * q) * FSTR + rr]     = f.y;
    sr[(2 * q + 1) * FSTR + rr] = f.z;  si[(2 * q + 1) * FSTR + rr] = f.w;
  }
  fft512x8<true>(sr, si, twr, twi, t);
  int sb = img / 3, sc = img - 3 * sb;
  int dimg = ((sb + 4) & 7) * 3 + (sc + 1) % 3;
  float* xb = xmag + (size_t)dimg * NPIX + (c0 ^ 256);
  const int rg = t >> 2;                     // 0..63
  #pragma unroll
  for (int it = 0; it < 8; it++) {
    int row = 64 * it + rg;                  // consecutive row set
    float a0 = sr[(2 * q) * FSTR + row],     b0 = si[(2 * q) * FSTR + row];
    float a1 = sr[(2 * q + 1) * FSTR + row], b1 = si[(2 * q + 1) * FSTR + row];
    *(float4*)(base + (size_t)row * 512 + 2 * q) = make_float4(a0, b0, a1, b1);
    float m0 = log10f(sqrtf(a0 * a0 + b0 * b0) + 1.0f);
    float m1 = log10f(sqrtf(a1 * a1 + b1 * b1) + 1.0f);
    *(float2*)(xb + (size_t)(row ^ 256) * 512 + 2 * q) = make_float2(m0, m1);
  }
}

// conv1: 6->16, 512x512, pad1, relu, 2x2 avgpool -> [b][16][256][256]
// grid (4, 32, 16). Double-buffered LDS staging, 1 ic per round.
__global__ __launch_bounds__(256) void k_conv1(const float* __restrict__ x,
                                               const float* __restrict__ xmag,
                                               const float* __restrict__ w1,
                                               const float* __restrict__ b1,
                                               float* __restrict__ out) {
  __shared__ float tile[2][18 * 132 + 8];
  const int t = threadIdx.x;
  const int tx = t & 31, ty = t >> 5;
  const int PC0 = blockIdx.x * 64;
  const int PR0 = blockIdx.y * 8;
  const int b  = blockIdx.z >> 1;
  const int og = (blockIdx.z & 1) * 8;
  const int R0 = PR0 * 2 - 1;
  const int C0 = PC0 * 2 - 1;

  int li[10], gi[10];
  bool okf[10];
  #pragma unroll
  for (int k = 0; k < 10; k++) {
    int e = t + 256 * k;
    bool valid = e < 2340;
    int i = e / 130, j = e - i * 130;
    int rr = R0 + i, cc = C0 + j;
    bool ok = valid && ((unsigned)rr < 512u) && ((unsigned)cc < 512u);
    li[k] = valid ? (i * 132 + j) : (18 * 132);
    gi[k] = ok ? (rr * 512 + cc) : 0;
    okf[k] = ok;
  }

  float acc[8][8];
  #pragma unroll
  for (int o = 0; o < 8; o++)
    #pragma unroll
    for (int q = 0; q < 8; q++) acc[o][q] = 0.0f;

  const float* xb = x + (size_t)(b * 3) * NPIX;
  const float* mb = xmag + (size_t)(b * 3) * NPIX;

  float ld[10];
  #pragma unroll
  for (int k = 0; k < 10; k++) ld[k] = okf[k] ? xb[gi[k]] : 0.0f;
  #pragma unroll
  for (int k = 0; k < 10; k++) tile[0][li[k]] = ld[k];
  __syncthreads();

  for (int ic = 0; ic < 6; ic++) {
    if (ic < 5) {
      const float* sn = (ic + 1 < 3) ? (xb + (size_t)(ic + 1) * NPIX)
                                     : (mb + (size_t)(ic - 2) * NPIX);
      #pragma unroll
      for (int k = 0; k < 10; k++) ld[k] = okf[k] ? sn[gi[k]] : 0.0f;
    }
    const float* cur = tile[ic & 1];
    float patch[4][6];
    #pragma unroll
    for (int dy = 0; dy < 4; dy++) {
      const float* rp = cur + (2 * ty + dy) * 132 + 4 * tx;
      float4 f = *(const float4*)rp;
      float2 g = *(const float2*)(rp + 4);
      patch[dy][0] = f.x; patch[dy][1] = f.y; patch[dy][2] = f.z;
      patch[dy][3] = f.w; patch[dy][4] = g.x; patch[dy][5] = g.y;
    }
    #pragma unroll
    for (int o = 0; o < 8; o++) {
      const float* wk = w1 + (size_t)((og + o) * 6 + ic) * 9;
      float k0 = wk[0], k1 = wk[1], k2 = wk[2], k3 = wk[3], k4 = wk[4],
            k5 = wk[5], k6 = wk[6], k7 = wk[7], k8 = wk[8];
      #pragma unroll
      for (int py = 0; py < 2; py++)
        #pragma unroll
        for (int px = 0; px < 4; px++) {
          acc[o][py * 4 + px] +=
              k0 * patch[py][px]     + k1 * patch[py][px + 1]     + k2 * patch[py][px + 2]
            + k3 * patch[py + 1][px] + k4 * patch[py + 1][px + 1] + k5 * patch[py + 1][px + 2]
            + k6 * patch[py + 2][px] + k7 * patch[py + 2][px + 1] + k8 * patch[py + 2][px + 2];
        }
    }
    if (ic < 5) {
      __syncthreads();
      float* nxt = tile[(ic + 1) & 1];
      #pragma unroll
      for (int k = 0; k < 10; k++) nxt[li[k]] = ld[k];
      __syncthreads();
    }
  }
  #pragma unroll
  for (int o = 0; o < 8; o++) {
    float bias = b1[og + o];
    float p0 = fmaxf(acc[o][0] + bias, 0.0f) + fmaxf(acc[o][1] + bias, 0.0f)
             + fmaxf(acc[o][4] + bias, 0.0f) + fmaxf(acc[o][5] + bias, 0.0f);
    float p1 = fmaxf(acc[o][2] + bias, 0.0f) + fmaxf(acc[o][3] + bias, 0.0f)
             + fmaxf(acc[o][6] + bias, 0.0f) + fmaxf(acc[o][7] + bias, 0.0f);
    float2* q = (float2*)(out + ((size_t)(b * 16 + og + o) * 256 + PR0 + ty) * 256 + PC0 + 2 * tx);
    *q = make_float2(p0 * 0.25f, p1 * 0.25f);
  }
}

// conv2: 16->32, 256x256, pad1, relu, pool -> 9 stats per (b,oc) -> S[b][32][9].
// grid (4, 16, 32) = 2048 blocks. Thread: 1 pooled col x 8 oc. Tile 18x66.
__global__ __launch_bounds__(256) void k_conv2(const float* __restrict__ in,
                                               const float* __restrict__ w2,
                                               const float* __restrict__ b2,
                                               float* __restrict__ S) {
  __shared__ float tile[2][18 * 68 + 8];
  __shared__ float wsum[4][8];
  const int t = threadIdx.x;
  const int tx = t & 31, ty = t >> 5;
  const int bx = blockIdx.x, by = blockIdx.y;
  const int PC0 = bx * 32;
  const int PR0 = by * 8;
  const int b  = blockIdx.z >> 2;
  const int og = (blockIdx.z & 3) * 8;
  const int R0 = PR0 * 2 - 1;
  const int C0 = PC0 * 2 - 1;

  int li[5], gi[5];
  bool okf[5];
  #pragma unroll
  for (int k = 0; k < 5; k++) {
    int e = t + 256 * k;
    bool valid = e < 1188;
    int i = e / 66, j = e - 66 * i;
    int rr = R0 + i, cc = C0 + j;
    bool ok = valid && ((unsigned)rr < 256u) && ((unsigned)cc < 256u);
    li[k] = valid ? (i * 68 + j) : (18 * 68);
    gi[k] = ok ? (rr * 256 + cc) : 0;
    okf[k] = ok;
  }

  float acc[8][4];
  #pragma unroll
  for (int o = 0; o < 8; o++)
    #pragma unroll
    for (int q = 0; q < 4; q++) acc[o][q] = 0.0f;

  const float* inb = in + (size_t)(b * 16) * 65536;

  float ld[5];
  #pragma unroll
  for (int k = 0; k < 5; k++) ld[k] = okf[k] ? inb[gi[k]] : 0.0f;
  #pragma unroll
  for (int k = 0; k < 5; k++) tile[0][li[k]] = ld[k];
  __syncthreads();

  for (int ic = 0; ic < 16; ic++) {
    if (ic < 15) {
      const float* sn = inb + (size_t)(ic + 1) * 65536;
      #pragma unroll
      for (int k = 0; k < 5; k++) ld[k] = okf[k] ? sn[gi[k]] : 0.0f;
    }
    const float* cur = tile[ic & 1];
    float patch[4][4];
    #pragma unroll
    for (int dy = 0; dy < 4; dy++) {
      const float* rp = cur + (2 * ty + dy) * 68 + 2 * tx;
      float2 f0 = *(const float2*)rp;
      float2 f1 = *(const float2*)(rp + 2);
      patch[dy][0] = f0.x; patch[dy][1] = f0.y;
      patch[dy][2] = f1.x; patch[dy][3] = f1.y;
    }
    #pragma unroll
    for (int o = 0; o < 8; o++) {
      const float* wk = w2 + (size_t)((og + o) * 16 + ic) * 9;
      float k0 = wk[0], k1 = wk[1], k2 = wk[2], k3 = wk[3], k4 = wk[4],
            k5 = wk[5], k6 = wk[6], k7 = wk[7], k8 = wk[8];
      #pragma unroll
      for (int py = 0; py < 2; py++)
        #pragma unroll
        for (int px = 0; px < 2; px++) {
          acc[o][py * 2 + px] +=
              k0 * patch[py][px]     + k1 * patch[py][px + 1]     + k2 * patch[py][px + 2]
            + k3 * patch[py + 1][px] + k4 * patch[py + 1][px + 1] + k5 * patch[py + 1][px + 2]
            + k6 * patch[py + 2][px] + k7 * patch[py + 2][px + 1] + k8 * patch[py + 2][px + 2];
        }
    }
    if (ic < 15) {
      __syncthreads();
      float* nxt = tile[(ic + 1) & 1];
      #pragma unroll
      for (int k = 0; k < 5; k++) nxt[li[k]] = ld[k];
      __syncthreads();
    }
  }

  const int lane = t & 63;
  const int wid = t >> 6;
  float* Sb0 = S + (size_t)(b * 32 + og) * 9;
  #pragma unroll
  for (int o = 0; o < 8; o++) {
    float bias = b2[og + o];
    float v = (fmaxf(acc[o][0] + bias, 0.0f) + fmaxf(acc[o][1] + bias, 0.0f)
             + fmaxf(acc[o][2] + bias, 0.0f) + fmaxf(acc[o][3] + bias, 0.0f)) * 0.25f;
    float* Sb = Sb0 + o * 9;
    float ts = v;
    #pragma unroll
    for (int off = 32; off > 0; off >>= 1) ts += __shfl_down(ts, off);
    if (lane == 0) wsum[wid][o] = ts;
    if (by == 0) {
      float e = (ty == 0) ? v : 0.0f;
      #pragma unroll
      for (int off = 32; off > 0; off >>= 1) e += __shfl_down(e, off);
      if (lane == 0) atomicAdd(&Sb[1], e);
    }
    if (by == 15) {
      float e = (ty == 7) ? v : 0.0f;
      #pragma unroll
      for (int off = 32; off > 0; off >>= 1) e += __shfl_down(e, off);
      if (lane == 0) atomicAdd(&Sb[2], e);
    }
    if (bx == 0 && tx == 0)  atomicAdd(&Sb[3], v);
    if (bx == 3 && tx == 31) atomicAdd(&Sb[4], v);
    if (bx == 0 && by == 0  && t == 0)   Sb[5] = v;
    if (bx == 3 && by == 0  && t == 31)  Sb[6] = v;
    if (bx == 0 && by == 15 && t == 224) Sb[7] = v;
    if (bx == 3 && by == 15 && t == 255) Sb[8] = v;
  }
  __syncthreads();
  if (t < 8)
    atomicAdd(&Sb0[t * 9], wsum[0][t] + wsum[1][t] + wsum[2][t] + wsum[3][t]);
}

// k_fc: stats -> conv3-mean (matvec over 288 window sums) -> FC1 -> FC2 -> leaky.
__global__ __launch_bounds__(256) void k_fc(const float* __restrict__ S,
                                            const float* __restrict__ w3,
                                            const float* __restrict__ b3,
                                            const float* __restrict__ fw1,
                                            const float* __restrict__ fb1,
                                            const float* __restrict__ fw2,
                                            const float* __restrict__ fb2,
                                            float* __restrict__ vs_out) {
  __shared__ float Sp[2304];
  __shared__ float y[512];
  __shared__ float h1[2048];
  int t = threadIdx.x;
  for (int e = t; e < 2304; e += 256) {
    int cell = e / 9, k = e - 9 * cell;
    int dy = k / 3, dx = k - 3 * dy;
    const float* s = S + cell * 9;
    float v = s[0];
    if (dy == 0) v -= s[2];
    if (dy == 2) v -= s[1];
    if (dx == 0) v -= s[4];
    if (dx == 2) v -= s[3];
    if (dy == 0 && dx == 0) v += s[8];
    if (dy == 0 && dx == 2) v += s[7];
    if (dy == 2 && dx == 0) v += s[6];
    if (dy == 2 && dx == 2) v += s[5];
    Sp[e] = v;
  }
  __syncthreads();
  for (int e = t; e < 512; e += 256) {
    int b = e >> 6, o = e & 63;
    const float* wrow = w3 + (size_t)o * 288;
    const float* sp = Sp + b * 288;
    float s = 0.0f;
    #pragma unroll 4
    for (int k = 0; k < 288; k++) s += wrow[k] * sp[k];
    y[e] = b3[o] + s * (1.0f / 16384.0f);
  }
  __syncthreads();
  for (int e = t; e < 2048; e += 256) {
    int b = e >> 8, j = e & 255;
    float s = fb1[j];
    for (int k = 0; k < 64; k++) s += y[b * 64 + k] * fw1[j * 64 + k];
    h1[e] = s;
  }
  __syncthreads();
  for (int e = t; e < 800; e += 256) {
    int b = e / 100, i = e - 100 * b;
    float s = fb2[i];
    for (int j = 0; j < 256; j++) s += h1[b * 256 + j] * fw2[i * 256 + j];
    vs_out[e] = (s >= 0.0f) ? s : 0.01f * s;
  }
}

// fq_mask[b][h][w] = value_set[b][searchsorted(radius_set, dist(h,w), 'left').clip(0,99)]
__global__ __launch_bounds__(256) void k_mask(const float* __restrict__ vs,
                                              float* __restrict__ fq_mask) {
  int idx = blockIdx.x * 256 + threadIdx.x;
  int h = idx >> 9, w = idx & 511;
  float da = (float)h - 256.0f, db = (float)w - 256.0f;
  float dist = sqrtf(da * da + db * db);
  int lo = 0, hi = 100;
  while (lo < hi) {
    int mid = (lo + hi) >> 1;
    float r = (362.03867196751236f * (float)(mid + 1)) * 0.01f;
    if (r < dist) lo = mid + 1; else hi = mid;
  }
  int bin = lo > 99 ? 99 : lo;
  #pragma unroll
  for (int b = 0; b < 8; b++)
    fq_mask[(size_t)b * NPIX + idx] = vs[b * 100 + bin];
}

// inverse FFT over 8 rows per block, spectrum modulation fused on load.
__global__ __launch_bounds__(256) void k_ifft_rows_mod(float2* __restrict__ xf,
                                                       const float* __restrict__ fq_mask) {
  __shared__ float sr[8 * FSTR], si[8 * FSTR], twr[256], twi[256];
  int t = threadIdx.x;
  int img = blockIdx.x >> 6;
  int r0 = (blockIdx.x & 63) << 3;
  int bm = ((img / 3) + 4) & 7;
  init_tw(twr, twi, t);
  const float* mbase = fq_mask + (size_t)bm * NPIX;
  float4* base4 = (float4*)(xf + (size_t)img * NPIX + (size_t)r0 * 512);
  for (int e = t; e < 2048; e += 256) {
    int u = (e & 3) | (((e >> 2) & 15) << 3) | (((e >> 6) & 1) << 2) | (((e >> 7) & 1) << 7);
    int row = e >> 8;
    float4 f = base4[row * 256 + u];
    int p0 = 2 * u;
    const float* mrow = mbase + (size_t)((r0 + row + 256) & 511) * 512;
    float2 m = *(const float2*)(mrow + ((p0 + 256) & 511));
    int rr0 = brev9(p0);
    float* cr = sr + row * FSTR;
    float* ci = si + row * FSTR;
    cr[rr0]       = f.x * m.x;  ci[rr0]       = f.y * m.x;
    cr[rr0 + 256] = f.z * m.y;  ci[rr0 + 256] = f.w * m.y;
  }
  fft512x8<false>(sr, si, twr, twi, t);
  for (int e = t; e < 2048; e += 256) {
    int row = e >> 8, u = e & 255;
    const float* cr = sr + row * FSTR;
    const float* ci = si + row * FSTR;
    base4[e] = make_float4(cr[2 * u], ci[2 * u], cr[2 * u + 1], ci[2 * u + 1]);
  }
}

// inverse FFT over 8 columns per block, scale 1/N, clip -> lowpass.
// Same txn-packed lane maps as k_fft_cols.
__global__ __launch_bounds__(256) void k_ifft_cols_out(const float2* __restrict__ xf,
                                                       float* __restrict__ lowpass) {
  __shared__ float sr[8 * FSTR], si[8 * FSTR], twr[256], twi[256];
  int t = threadIdx.x;
  int img = blockIdx.x >> 6;
  int c0 = (blockIdx.x & 63) << 3;
  init_tw(twr, twi, t);
  const float2* base = xf + (size_t)img * NPIX + c0;
  const int q = t & 3;
  const int j = (t >> 2) & 15;
  const int w = t >> 6;
  #pragma unroll
  for (int it = 0; it < 8; it++) {
    int row = 32 * j + 4 * it + w;
    float4 f = *(const float4*)(base + (size_t)row * 512 + 2 * q);
    int rr = brev9(row);
    sr[(2 * q) * FSTR + rr]     = f.x;  si[(2 * q) * FSTR + rr]     = f.y;
    sr[(2 * q + 1) * FSTR + rr] = f.z;  si[(2 * q + 1) * FSTR + rr] = f.w;
  }
  fft512x8<false>(sr, si, twr, twi, t);
  const float sc = 1.0f / 262144.0f;
  float* obase = lowpass + (size_t)img * NPIX + c0;
  const int rg = t >> 2;
  #pragma unroll
  for (int it = 0; it < 8; it++) {
    int row = 64 * it + rg;
    float v0 = fminf(fmaxf(sr[(2 * q) * FSTR + row] * sc, 0.0f), 1.0f);
    float v1 = fminf(fmaxf(sr[(2 * q + 1) * FSTR + row] * sc, 0.0f), 1.0f);
    *(float2*)(obase + (size_t)row * 512 + 2 * q) = make_float2(v0, v1);
  }
}

extern "C" void kernel_launch(void* const* d_in, const int* in_sizes, int n_in,
                              void* d_out, int out_size, void* d_ws, size_t ws_size,
                              hipStream_t stream) {
  const float* x   = (const float*)d_in[0];
  const float* w1  = (const float*)d_in[1];
  const float* b1  = (const float*)d_in[2];
  const float* w2  = (const float*)d_in[3];
  const float* b2  = (const float*)d_in[4];
  const float* w3  = (const float*)d_in[5];
  const float* b3  = (const float*)d_in[6];
  const float* fw1 = (const float*)d_in[7];
  const float* fb1 = (const float*)d_in[8];
  const float* fw2 = (const float*)d_in[9];
  const float* fb2 = (const float*)d_in[10];

  float* lowpass = (float*)d_out;            // 8*3*512*512
  float* fq_mask = lowpass + 6291456;        // 8*512*512
  float* vs      = fq_mask + 2097152;        // 8*100

  float* base    = (float*)d_ws;
  float2* xf     = (float2*)base;            // 12582912 floats
  float* xmag    = base + 12582912;          // 6291456 floats
  float* pooled1 = xmag + 6291456;           // 8388608 floats
  float* S       = pooled1 + 8388608;        // 8*32*9 = 2304 floats

  k_fft_rows<<<dim3(24 * 64), 256, 0, stream>>>(x, xf);
  k_fft_cols<<<dim3(24 * 64), 256, 0, stream>>>(xf, xmag);   // xmag fused

  k_conv1<<<dim3(4, 32, 16), 256, 0, stream>>>(x, xmag, w1, b1, pooled1);
  hipMemsetAsync(S, 0, 2304 * sizeof(float), stream);
  k_conv2<<<dim3(4, 16, 32), 256, 0, stream>>>(pooled1, w2, b2, S);

  k_fc<<<1, 256, 0, stream>>>(S, w3, b3, fw1, fb1, fw2, fb2, vs);
  k_mask<<<1024, 256, 0, stream>>>(vs, fq_mask);

  k_ifft_rows_mod<<<dim3(24 * 64), 256, 0, stream>>>(xf, fq_mask);
  k_ifft_cols_out<<<dim3(24 * 64), 256, 0, stream>>>(xf, lowpass);
}

// Round 9
// 392.775 us; speedup vs baseline: 1.9193x; 1.0450x over previous
//
#include <hip/hip_runtime.h>
#include <math.h>

#define NPIX 262144   // 512*512
#define FSTR 513      // LDS column stride for batch-8 FFT (pad 512+1)

__device__ __forceinline__ int brev9(int i) { return (int)(__brev((unsigned)i) >> 23); }

__device__ __forceinline__ void init_tw(float* twr, float* twi, int t) {
  if (t < 256) {
    float ang = -3.14159265358979323846f * (float)t / 256.0f;
    float s, c;
    sincosf(ang, &s, &c);
    twr[t] = c; twi[t] = s;
  }
}

// 8 x 512-pt FFTs in LDS, column-major: element p of FFT c at [c*FSTR + p].
// Radix-4 core: stages (0,1),(2,3),(4,5),(6,7) merged (4 LDS ops/elem per
// pair instead of 8, 1 barrier instead of 2), final radix-2 stage 8.
// Input must be stored radix-2 bit-reversed (brev9) by the caller.
template<bool FWD>
__device__ __forceinline__ void fft512x8(float* __restrict__ sr, float* __restrict__ si,
                                         const float* __restrict__ twr,
                                         const float* __restrict__ twi, int t) {
  const int c  = t >> 5;
  const int tq = t & 31;
  float* cr = sr + c * FSTR;
  float* ci = si + c * FSTR;
  #pragma unroll
  for (int sp = 0; sp < 4; sp++) {
    const int s = 2 * sp;
    const int h = 1 << s;
    __syncthreads();
    #pragma unroll
    for (int m = 0; m < 4; m++) {
      int q = tq + 32 * m;                    // quad id 0..127
      int j = q & (h - 1);
      int base = ((q >> s) << (s + 2)) | j;
      int i1 = j << (8 - s);                  // stage-s twiddle
      int i2 = j << (7 - s);                  // stage-(s+1) twiddle
      float w1r = twr[i1], w1i = FWD ? twi[i1] : -twi[i1];
      float w2r = twr[i2], w2i = FWD ? twi[i2] : -twi[i2];
      float ar = cr[base],         ai = ci[base];
      float br = cr[base + h],     bi = ci[base + h];
      float c2r = cr[base + 2*h],  c2i = ci[base + 2*h];
      float dr = cr[base + 3*h],   di = ci[base + 3*h];
      // stage s
      float wbr = br * w1r - bi * w1i, wbi = br * w1i + bi * w1r;
      float wdr = dr * w1r - di * w1i, wdi = dr * w1i + di * w1r;
      float t0r = ar + wbr,  t0i = ai + wbi;
      float t1r = ar - wbr,  t1i = ai - wbi;
      float t2r = c2r + wdr, t2i = c2i + wdi;
      float t3r = c2r - wdr, t3i = c2i - wdi;
      // stage s+1 ; w2' = w2 * (-i) fwd, (+i) inv
      float u2r = t2r * w2r - t2i * w2i, u2i = t2r * w2i + t2i * w2r;
      float v3r = t3r * w2r - t3i * w2i, v3i = t3r * w2i + t3i * w2r;
      float u3r = FWD ? v3i : -v3i;
      float u3i = FWD ? -v3r : v3r;
      cr[base]         = t0r + u2r;  ci[base]         = t0i + u2i;
      cr[base + 2*h]   = t0r - u2r;  ci[base + 2*h]   = t0i - u2i;
      cr[base + h]     = t1r + u3r;  ci[base + h]     = t1i + u3i;
      cr[base + 3*h]   = t1r - u3r;  ci[base + 3*h]   = t1i - u3i;
    }
  }
  // final radix-2 stage (s=8, half=256)
  __syncthreads();
  #pragma unroll
  for (int m = 0; m < 8; m++) {
    int k = tq + 32 * m;                      // 0..255 == j
    float wr = twr[k], wi = FWD ? twi[k] : -twi[k];
    float vr = cr[k + 256], vi = ci[k + 256];
    float tr = vr * wr - vi * wi;
    float ti = vr * wi + vi * wr;
    float ur = cr[k], ui = ci[k];
    cr[k] = ur + tr;        ci[k] = ui + ti;
    cr[k + 256] = ur - tr;  ci[k + 256] = ui - ti;
  }
  __syncthreads();
}

// forward FFT over 8 contiguous rows per block (real input).
__global__ __launch_bounds__(256) void k_fft_rows(const float* __restrict__ x,
                                                  float2* __restrict__ xf) {
  __shared__ float sr[8 * FSTR], si[8 * FSTR], twr[256], twi[256];
  int t = threadIdx.x;
  int img = blockIdx.x >> 6;
  int r0 = (blockIdx.x & 63) << 3;
  init_tw(twr, twi, t);
  const float4* p4 = (const float4*)(x + (size_t)img * NPIX + (size_t)r0 * 512);
  for (int e = t; e < 1024; e += 256) {
    int row = e >> 7, w = e & 127;
    float4 f = p4[e];
    float* cr = sr + row * FSTR;
    float* ci = si + row * FSTR;
    int p = 4 * w;
    cr[brev9(p)]     = f.x;  ci[brev9(p)]     = 0.0f;
    cr[brev9(p + 1)] = f.y;  ci[brev9(p + 1)] = 0.0f;
    cr[brev9(p + 2)] = f.z;  ci[brev9(p + 2)] = 0.0f;
    cr[brev9(p + 3)] = f.w;  ci[brev9(p + 3)] = 0.0f;
  }
  fft512x8<true>(sr, si, twr, twi, t);
  float4* q4 = (float4*)(xf + (size_t)img * NPIX + (size_t)r0 * 512);
  for (int e = t; e < 2048; e += 256) {
    int row = e >> 8, u = e & 255;
    const float* cr = sr + row * FSTR;
    const float* ci = si + row * FSTR;
    q4[e] = make_float4(cr[2 * u], ci[2 * u], cr[2 * u + 1], ci[2 * u + 1]);
  }
}

// forward FFT over 8 adjacent columns per block (in-place on xf), xmag fused.
// Lane map packs global txns: q=t&3 -> 4 lanes cover one 64B row (16 txn/instr).
__global__ __launch_bounds__(256) void k_fft_cols(float2* __restrict__ xf,
                                                  float* __restrict__ xmag) {
  __shared__ float sr[8 * FSTR], si[8 * FSTR], twr[256], twi[256];
  int t = threadIdx.x;
  int img = blockIdx.x >> 6;
  int c0 = (blockIdx.x & 63) << 3;
  init_tw(twr, twi, t);
  float2* base = xf + (size_t)img * NPIX + c0;
  const int q = t & 3;
  const int j = (t >> 2) & 15;
  const int w = t >> 6;
  #pragma unroll
  for (int it = 0; it < 8; it++) {
    int row = 32 * j + 4 * it + w;           // stride-32 row set
    float4 f = *(const float4*)(base + (size_t)row * 512 + 2 * q);
    int rr = brev9(row);
    sr[(2 * q) * FSTR + rr]     = f.x;  si[(2 * q) * FSTR + rr]     = f.y;
    sr[(2 * q + 1) * FSTR + rr] = f.z;  si[(2 * q + 1) * FSTR + rr] = f.w;
  }
  fft512x8<true>(sr, si, twr, twi, t);
  int sb = img / 3, sc = img - 3 * sb;
  int dimg = ((sb + 4) & 7) * 3 + (sc + 1) % 3;
  float* xb = xmag + (size_t)dimg * NPIX + (c0 ^ 256);
  const int rg = t >> 2;                     // 0..63
  #pragma unroll
  for (int it = 0; it < 8; it++) {
    int row = 64 * it + rg;                  // consecutive row set
    float a0 = sr[(2 * q) * FSTR + row],     b0 = si[(2 * q) * FSTR + row];
    float a1 = sr[(2 * q + 1) * FSTR + row], b1 = si[(2 * q + 1) * FSTR + row];
    *(float4*)(base + (size_t)row * 512 + 2 * q) = make_float4(a0, b0, a1, b1);
    float m0 = log10f(sqrtf(a0 * a0 + b0 * b0) + 1.0f);
    float m1 = log10f(sqrtf(a1 * a1 + b1 * b1) + 1.0f);
    *(float2*)(xb + (size_t)(row ^ 256) * 512 + 2 * q) = make_float2(m0, m1);
  }
}

// conv1: 6->16, 512x512, pad1, relu, 2x2 avgpool -> [b][16][256][256]
// grid (4, 32, 16). Double-buffered, ONE barrier per ic (the pre-write
// barrier is redundant: nxt was last read in round ic-1 which ended with a
// barrier).
__global__ __launch_bounds__(256) void k_conv1(const float* __restrict__ x,
                                               const float* __restrict__ xmag,
                                               const float* __restrict__ w1,
                                               const float* __restrict__ b1,
                                               float* __restrict__ out) {
  __shared__ float tile[2][18 * 132 + 8];
  const int t = threadIdx.x;
  const int tx = t & 31, ty = t >> 5;
  const int PC0 = blockIdx.x * 64;
  const int PR0 = blockIdx.y * 8;
  const int b  = blockIdx.z >> 1;
  const int og = (blockIdx.z & 1) * 8;
  const int R0 = PR0 * 2 - 1;
  const int C0 = PC0 * 2 - 1;

  int li[10], gi[10];
  bool okf[10];
  #pragma unroll
  for (int k = 0; k < 10; k++) {
    int e = t + 256 * k;
    bool valid = e < 2340;
    int i = e / 130, j = e - i * 130;
    int rr = R0 + i, cc = C0 + j;
    bool ok = valid && ((unsigned)rr < 512u) && ((unsigned)cc < 512u);
    li[k] = valid ? (i * 132 + j) : (18 * 132);
    gi[k] = ok ? (rr * 512 + cc) : 0;
    okf[k] = ok;
  }

  float acc[8][8];
  #pragma unroll
  for (int o = 0; o < 8; o++)
    #pragma unroll
    for (int q = 0; q < 8; q++) acc[o][q] = 0.0f;

  const float* xb = x + (size_t)(b * 3) * NPIX;
  const float* mb = xmag + (size_t)(b * 3) * NPIX;

  float ld[10];
  #pragma unroll
  for (int k = 0; k < 10; k++) ld[k] = okf[k] ? xb[gi[k]] : 0.0f;
  #pragma unroll
  for (int k = 0; k < 10; k++) tile[0][li[k]] = ld[k];
  __syncthreads();

  for (int ic = 0; ic < 6; ic++) {
    if (ic < 5) {
      const float* sn = (ic + 1 < 3) ? (xb + (size_t)(ic + 1) * NPIX)
                                     : (mb + (size_t)(ic - 2) * NPIX);
      #pragma unroll
      for (int k = 0; k < 10; k++) ld[k] = okf[k] ? sn[gi[k]] : 0.0f;
    }
    const float* cur = tile[ic & 1];
    float patch[4][6];
    #pragma unroll
    for (int dy = 0; dy < 4; dy++) {
      const float* rp = cur + (2 * ty + dy) * 132 + 4 * tx;
      float4 f = *(const float4*)rp;
      float2 g = *(const float2*)(rp + 4);
      patch[dy][0] = f.x; patch[dy][1] = f.y; patch[dy][2] = f.z;
      patch[dy][3] = f.w; patch[dy][4] = g.x; patch[dy][5] = g.y;
    }
    #pragma unroll
    for (int o = 0; o < 8; o++) {
      const float* wk = w1 + (size_t)((og + o) * 6 + ic) * 9;
      float k0 = wk[0], k1 = wk[1], k2 = wk[2], k3 = wk[3], k4 = wk[4],
            k5 = wk[5], k6 = wk[6], k7 = wk[7], k8 = wk[8];
      #pragma unroll
      for (int py = 0; py < 2; py++)
        #pragma unroll
        for (int px = 0; px < 4; px++) {
          acc[o][py * 4 + px] +=
              k0 * patch[py][px]     + k1 * patch[py][px + 1]     + k2 * patch[py][px + 2]
            + k3 * patch[py + 1][px] + k4 * patch[py + 1][px + 1] + k5 * patch[py + 1][px + 2]
            + k6 * patch[py + 2][px] + k7 * patch[py + 2][px + 1] + k8 * patch[py + 2][px + 2];
        }
    }
    if (ic < 5) {
      float* nxt = tile[(ic + 1) & 1];
      #pragma unroll
      for (int k = 0; k < 10; k++) nxt[li[k]] = ld[k];
      __syncthreads();
    }
  }
  #pragma unroll
  for (int o = 0; o < 8; o++) {
    float bias = b1[og + o];
    float p0 = fmaxf(acc[o][0] + bias, 0.0f) + fmaxf(acc[o][1] + bias, 0.0f)
             + fmaxf(acc[o][4] + bias, 0.0f) + fmaxf(acc[o][5] + bias, 0.0f);
    float p1 = fmaxf(acc[o][2] + bias, 0.0f) + fmaxf(acc[o][3] + bias, 0.0f)
             + fmaxf(acc[o][6] + bias, 0.0f) + fmaxf(acc[o][7] + bias, 0.0f);
    float2* q = (float2*)(out + ((size_t)(b * 16 + og + o) * 256 + PR0 + ty) * 256 + PC0 + 2 * tx);
    *q = make_float2(p0 * 0.25f, p1 * 0.25f);
  }
}

// conv2: 16->32, 256x256, pad1, relu, pool -> 9 stats per (b,oc) -> S[b][32][9].
// grid (4, 16, 32). ONE barrier per ic.
__global__ __launch_bounds__(256) void k_conv2(const float* __restrict__ in,
                                               const float* __restrict__ w2,
                                               const float* __restrict__ b2,
                                               float* __restrict__ S) {
  __shared__ float tile[2][18 * 68 + 8];
  __shared__ float wsum[4][8];
  const int t = threadIdx.x;
  const int tx = t & 31, ty = t >> 5;
  const int bx = blockIdx.x, by = blockIdx.y;
  const int PC0 = bx * 32;
  const int PR0 = by * 8;
  const int b  = blockIdx.z >> 2;
  const int og = (blockIdx.z & 3) * 8;
  const int R0 = PR0 * 2 - 1;
  const int C0 = PC0 * 2 - 1;

  int li[5], gi[5];
  bool okf[5];
  #pragma unroll
  for (int k = 0; k < 5; k++) {
    int e = t + 256 * k;
    bool valid = e < 1188;
    int i = e / 66, j = e - 66 * i;
    int rr = R0 + i, cc = C0 + j;
    bool ok = valid && ((unsigned)rr < 256u) && ((unsigned)cc < 256u);
    li[k] = valid ? (i * 68 + j) : (18 * 68);
    gi[k] = ok ? (rr * 256 + cc) : 0;
    okf[k] = ok;
  }

  float acc[8][4];
  #pragma unroll
  for (int o = 0; o < 8; o++)
    #pragma unroll
    for (int q = 0; q < 4; q++) acc[o][q] = 0.0f;

  const float* inb = in + (size_t)(b * 16) * 65536;

  float ld[5];
  #pragma unroll
  for (int k = 0; k < 5; k++) ld[k] = okf[k] ? inb[gi[k]] : 0.0f;
  #pragma unroll
  for (int k = 0; k < 5; k++) tile[0][li[k]] = ld[k];
  __syncthreads();

  for (int ic = 0; ic < 16; ic++) {
    if (ic < 15) {
      const float* sn = inb + (size_t)(ic + 1) * 65536;
      #pragma unroll
      for (int k = 0; k < 5; k++) ld[k] = okf[k] ? sn[gi[k]] : 0.0f;
    }
    const float* cur = tile[ic & 1];
    float patch[4][4];
    #pragma unroll
    for (int dy = 0; dy < 4; dy++) {
      const float* rp = cur + (2 * ty + dy) * 68 + 2 * tx;
      float2 f0 = *(const float2*)rp;
      float2 f1 = *(const float2*)(rp + 2);
      patch[dy][0] = f0.x; patch[dy][1] = f0.y;
      patch[dy][2] = f1.x; patch[dy][3] = f1.y;
    }
    #pragma unroll
    for (int o = 0; o < 8; o++) {
      const float* wk = w2 + (size_t)((og + o) * 16 + ic) * 9;
      float k0 = wk[0], k1 = wk[1], k2 = wk[2], k3 = wk[3], k4 = wk[4],
            k5 = wk[5], k6 = wk[6], k7 = wk[7], k8 = wk[8];
      #pragma unroll
      for (int py = 0; py < 2; py++)
        #pragma unroll
        for (int px = 0; px < 2; px++) {
          acc[o][py * 2 + px] +=
              k0 * patch[py][px]     + k1 * patch[py][px + 1]     + k2 * patch[py][px + 2]
            + k3 * patch[py + 1][px] + k4 * patch[py + 1][px + 1] + k5 * patch[py + 1][px + 2]
            + k6 * patch[py + 2][px] + k7 * patch[py + 2][px + 1] + k8 * patch[py + 2][px + 2];
        }
    }
    if (ic < 15) {
      float* nxt = tile[(ic + 1) & 1];
      #pragma unroll
      for (int k = 0; k < 5; k++) nxt[li[k]] = ld[k];
      __syncthreads();
    }
  }

  const int lane = t & 63;
  const int wid = t >> 6;
  float* Sb0 = S + (size_t)(b * 32 + og) * 9;
  #pragma unroll
  for (int o = 0; o < 8; o++) {
    float bias = b2[og + o];
    float v = (fmaxf(acc[o][0] + bias, 0.0f) + fmaxf(acc[o][1] + bias, 0.0f)
             + fmaxf(acc[o][2] + bias, 0.0f) + fmaxf(acc[o][3] + bias, 0.0f)) * 0.25f;
    float* Sb = Sb0 + o * 9;
    float ts = v;
    #pragma unroll
    for (int off = 32; off > 0; off >>= 1) ts += __shfl_down(ts, off);
    if (lane == 0) wsum[wid][o] = ts;
    if (by == 0) {
      float e = (ty == 0) ? v : 0.0f;
      #pragma unroll
      for (int off = 32; off > 0; off >>= 1) e += __shfl_down(e, off);
      if (lane == 0) atomicAdd(&Sb[1], e);
    }
    if (by == 15) {
      float e = (ty == 7) ? v : 0.0f;
      #pragma unroll
      for (int off = 32; off > 0; off >>= 1) e += __shfl_down(e, off);
      if (lane == 0) atomicAdd(&Sb[2], e);
    }
    if (bx == 0 && tx == 0)  atomicAdd(&Sb[3], v);
    if (bx == 3 && tx == 31) atomicAdd(&Sb[4], v);
    if (bx == 0 && by == 0  && t == 0)   Sb[5] = v;
    if (bx == 3 && by == 0  && t == 31)  Sb[6] = v;
    if (bx == 0 && by == 15 && t == 224) Sb[7] = v;
    if (bx == 3 && by == 15 && t == 255) Sb[8] = v;
  }
  __syncthreads();
  if (t < 8)
    atomicAdd(&Sb0[t * 9], wsum[0][t] + wsum[1][t] + wsum[2][t] + wsum[3][t]);
}

// k_fc: stats -> conv3-mean (matvec over 288 window sums) -> FC1 -> FC2 -> leaky.
__global__ __launch_bounds__(256) void k_fc(const float* __restrict__ S,
                                            const float* __restrict__ w3,
                                            const float* __restrict__ b3,
                                            const float* __restrict__ fw1,
                                            const float* __restrict__ fb1,
                                            const float* __restrict__ fw2,
                                            const float* __restrict__ fb2,
                                            float* __restrict__ vs_out) {
  __shared__ float Sp[2304];
  __shared__ float y[512];
  __shared__ float h1[2048];
  int t = threadIdx.x;
  for (int e = t; e < 2304; e += 256) {
    int cell = e / 9, k = e - 9 * cell;
    int dy = k / 3, dx = k - 3 * dy;
    const float* s = S + cell * 9;
    float v = s[0];
    if (dy == 0) v -= s[2];
    if (dy == 2) v -= s[1];
    if (dx == 0) v -= s[4];
    if (dx == 2) v -= s[3];
    if (dy == 0 && dx == 0) v += s[8];
    if (dy == 0 && dx == 2) v += s[7];
    if (dy == 2 && dx == 0) v += s[6];
    if (dy == 2 && dx == 2) v += s[5];
    Sp[e] = v;
  }
  __syncthreads();
  for (int e = t; e < 512; e += 256) {
    int b = e >> 6, o = e & 63;
    const float* wrow = w3 + (size_t)o * 288;
    const float* sp = Sp + b * 288;
    float s = 0.0f;
    #pragma unroll 4
    for (int k = 0; k < 288; k++) s += wrow[k] * sp[k];
    y[e] = b3[o] + s * (1.0f / 16384.0f);
  }
  __syncthreads();
  for (int e = t; e < 2048; e += 256) {
    int b = e >> 8, j = e & 255;
    float s = fb1[j];
    for (int k = 0; k < 64; k++) s += y[b * 64 + k] * fw1[j * 64 + k];
    h1[e] = s;
  }
  __syncthreads();
  for (int e = t; e < 800; e += 256) {
    int b = e / 100, i = e - 100 * b;
    float s = fb2[i];
    for (int j = 0; j < 256; j++) s += h1[b * 256 + j] * fw2[i * 256 + j];
    vs_out[e] = (s >= 0.0f) ? s : 0.01f * s;
  }
}

// fq_mask[b][h][w] = value_set[b][searchsorted(radius_set, dist(h,w), 'left').clip(0,99)]
__global__ __launch_bounds__(256) void k_mask(const float* __restrict__ vs,
                                              float* __restrict__ fq_mask) {
  int idx = blockIdx.x * 256 + threadIdx.x;
  int h = idx >> 9, w = idx & 511;
  float da = (float)h - 256.0f, db = (float)w - 256.0f;
  float dist = sqrtf(da * da + db * db);
  int lo = 0, hi = 100;
  while (lo < hi) {
    int mid = (lo + hi) >> 1;
    float r = (362.03867196751236f * (float)(mid + 1)) * 0.01f;
    if (r < dist) lo = mid + 1; else hi = mid;
  }
  int bin = lo > 99 ? 99 : lo;
  #pragma unroll
  for (int b = 0; b < 8; b++)
    fq_mask[(size_t)b * NPIX + idx] = vs[b * 100 + bin];
}

// inverse FFT over 8 rows per block, spectrum modulation fused on load.
__global__ __launch_bounds__(256) void k_ifft_rows_mod(float2* __restrict__ xf,
                                                       const float* __restrict__ fq_mask) {
  __shared__ float sr[8 * FSTR], si[8 * FSTR], twr[256], twi[256];
  int t = threadIdx.x;
  int img = blockIdx.x >> 6;
  int r0 = (blockIdx.x & 63) << 3;
  int bm = ((img / 3) + 4) & 7;
  init_tw(twr, twi, t);
  const float* mbase = fq_mask + (size_t)bm * NPIX;
  float4* base4 = (float4*)(xf + (size_t)img * NPIX + (size_t)r0 * 512);
  for (int e = t; e < 2048; e += 256) {
    int u = (e & 3) | (((e >> 2) & 15) << 3) | (((e >> 6) & 1) << 2) | (((e >> 7) & 1) << 7);
    int row = e >> 8;
    float4 f = base4[row * 256 + u];
    int p0 = 2 * u;
    const float* mrow = mbase + (size_t)((r0 + row + 256) & 511) * 512;
    float2 m = *(const float2*)(mrow + ((p0 + 256) & 511));
    int rr0 = brev9(p0);
    float* cr = sr + row * FSTR;
    float* ci = si + row * FSTR;
    cr[rr0]       = f.x * m.x;  ci[rr0]       = f.y * m.x;
    cr[rr0 + 256] = f.z * m.y;  ci[rr0 + 256] = f.w * m.y;
  }
  fft512x8<false>(sr, si, twr, twi, t);
  for (int e = t; e < 2048; e += 256) {
    int row = e >> 8, u = e & 255;
    const float* cr = sr + row * FSTR;
    const float* ci = si + row * FSTR;
    base4[e] = make_float4(cr[2 * u], ci[2 * u], cr[2 * u + 1], ci[2 * u + 1]);
  }
}

// inverse FFT over 8 columns per block, scale 1/N, clip -> lowpass.
__global__ __launch_bounds__(256) void k_ifft_cols_out(const float2* __restrict__ xf,
                                                       float* __restrict__ lowpass) {
  __shared__ float sr[8 * FSTR], si[8 * FSTR], twr[256], twi[256];
  int t = threadIdx.x;
  int img = blockIdx.x >> 6;
  int c0 = (blockIdx.x & 63) << 3;
  init_tw(twr, twi, t);
  const float2* base = xf + (size_t)img * NPIX + c0;
  const int q = t & 3;
  const int j = (t >> 2) & 15;
  const int w = t >> 6;
  #pragma unroll
  for (int it = 0; it < 8; it++) {
    int row = 32 * j + 4 * it + w;
    float4 f = *(const float4*)(base + (size_t)row * 512 + 2 * q);
    int rr = brev9(row);
    sr[(2 * q) * FSTR + rr]     = f.x;  si[(2 * q) * FSTR + rr]     = f.y;
    sr[(2 * q + 1) * FSTR + rr] = f.z;  si[(2 * q + 1) * FSTR + rr] = f.w;
  }
  fft512x8<false>(sr, si, twr, twi, t);
  const float sc = 1.0f / 262144.0f;
  float* obase = lowpass + (size_t)img * NPIX + c0;
  const int rg = t >> 2;
  #pragma unroll
  for (int it = 0; it < 8; it++) {
    int row = 64 * it + rg;
    float v0 = fminf(fmaxf(sr[(2 * q) * FSTR + row] * sc, 0.0f), 1.0f);
    float v1 = fminf(fmaxf(sr[(2 * q + 1) * FSTR + row] * sc, 0.0f), 1.0f);
    *(float2*)(obase + (size_t)row * 512 + 2 * q) = make_float2(v0, v1);
  }
}

extern "C" void kernel_launch(void* const* d_in, const int* in_sizes, int n_in,
                              void* d_out, int out_size, void* d_ws, size_t ws_size,
                              hipStream_t stream) {
  const float* x   = (const float*)d_in[0];
  const float* w1  = (const float*)d_in[1];
  const float* b1  = (const float*)d_in[2];
  const float* w2  = (const float*)d_in[3];
  const float* b2  = (const float*)d_in[4];
  const float* w3  = (const float*)d_in[5];
  const float* b3  = (const float*)d_in[6];
  const float* fw1 = (const float*)d_in[7];
  const float* fb1 = (const float*)d_in[8];
  const float* fw2 = (const float*)d_in[9];
  const float* fb2 = (const float*)d_in[10];

  float* lowpass = (float*)d_out;            // 8*3*512*512
  float* fq_mask = lowpass + 6291456;        // 8*512*512
  float* vs      = fq_mask + 2097152;        // 8*100

  float* base    = (float*)d_ws;
  float2* xf     = (float2*)base;            // 12582912 floats
  float* xmag    = base + 12582912;          // 6291456 floats
  float* pooled1 = xmag + 6291456;           // 8388608 floats
  float* S       = pooled1 + 8388608;        // 8*32*9 = 2304 floats

  k_fft_rows<<<dim3(24 * 64), 256, 0, stream>>>(x, xf);
  k_fft_cols<<<dim3(24 * 64), 256, 0, stream>>>(xf, xmag);   // xmag fused

  k_conv1<<<dim3(4, 32, 16), 256, 0, stream>>>(x, xmag, w1, b1, pooled1);
  hipMemsetAsync(S, 0, 2304 * sizeof(float), stream);
  k_conv2<<<dim3(4, 16, 32), 256, 0, stream>>>(pooled1, w2, b2, S);

  k_fc<<<1, 256, 0, stream>>>(S, w3, b3, fw1, fb1, fw2, fb2, vs);
  k_mask<<<1024, 256, 0, stream>>>(vs, fq_mask);

  k_ifft_rows_mod<<<dim3(24 * 64), 256, 0, stream>>>(xf, fq_mask);
  k_ifft_cols_out<<<dim3(24 * 64), 256, 0, stream>>>(xf, lowpass);
}